// Round 3
// baseline (5746.337 us; speedup 1.0000x reference)
//
#include <hip/hip_runtime.h>
#include <hip/hip_bf16.h>
#include <math.h>

typedef unsigned short u16;
typedef short bf16x8 __attribute__((ext_vector_type(8)));
typedef float f32x4 __attribute__((ext_vector_type(4)));

#define EMB   1024
#define HEADS 16
#define HD    64
#define LATD  256
#define FFND  4096
#define BATCH 2
#define SEQ   2048
#define TOK   (BATCH*SEQ)   // 4096

__device__ __forceinline__ float bf2f(u16 u) {
    union { unsigned int i; float f; } x; x.i = ((unsigned int)u) << 16; return x.f;
}
__device__ __forceinline__ u16 f2bf(float f) {
    union { float f; unsigned int i; } x; x.f = f;
    unsigned int i = x.i;
    unsigned int lsb = (i >> 16) & 1u;
    i += 0x7fffu + lsb;       // round-to-nearest-even
    return (u16)(i >> 16);
}

// ---------------------------------------------------------------- transpose + fp32->bf16 convert
// out[N][K] (bf16) = in[K][N] (fp32). 32x32 tiles, 256 threads.
__global__ __launch_bounds__(256) void transpose_cvt_kernel(
    const float* __restrict__ in, u16* __restrict__ out, int K, int N)
{
    __shared__ u16 t[32][33];
    const int bx = blockIdx.x * 32;  // n base
    const int by = blockIdx.y * 32;  // k base
    const int tx = threadIdx.x & 31;
    const int ty = threadIdx.x >> 5; // 0..7
#pragma unroll
    for (int i = 0; i < 32; i += 8)
        t[ty + i][tx] = f2bf(in[(size_t)(by + ty + i) * N + bx + tx]);
    __syncthreads();
#pragma unroll
    for (int i = 0; i < 32; i += 8)
        out[(size_t)(bx + ty + i) * K + by + tx] = t[tx][ty + i];
}

// ---------------------------------------------------------------- MFMA GEMM (B^T form)
// C[M,N] bf16 = A[M,K] @ W[K,N] + bias[N](fp32), W pre-transposed+converted: WT[N][K] bf16.
// A is fp32 (AF32=1) or bf16 (AF32=0). 128x128 tile, 4 waves, 4x4 16x16x32 MFMA, BK=32.
#define BM 128
#define BN 128
#define BK 32
#define LDK 40   // padded LDS K-stride (elements)

template <int ACT, int AF32>
__global__ __launch_bounds__(256, 2) void gemm_bt_kernel(
    const void* __restrict__ A, const u16* __restrict__ WT,
    const float* __restrict__ bias, u16* __restrict__ C,
    int M, int K, int N)
{
    __shared__ __align__(16) u16 Al[BM * LDK];
    __shared__ __align__(16) u16 Wl[BN * LDK];

    const int tid  = threadIdx.x;
    const int lane = tid & 63;
    const int wid  = tid >> 6;
    const int wm = wid >> 1, wn = wid & 1;
    const int col = lane & 15, qq = lane >> 4;
    const size_t bm = (size_t)blockIdx.y * BM;
    const size_t bn = (size_t)blockIdx.x * BN;

    const int sr = tid >> 1;         // staging row 0..127
    const int sh = (tid & 1) * 16;   // element offset 0/16 within BK

    f32x4 acc[4][4];
#pragma unroll
    for (int mt = 0; mt < 4; mt++)
#pragma unroll
        for (int nt = 0; nt < 4; nt++) acc[mt][nt] = (f32x4){0.f, 0.f, 0.f, 0.f};

    const float* agf = (const float*)A + (bm + sr) * (size_t)K + sh;
    const u16*   agb = (const u16*)A   + (bm + sr) * (size_t)K + sh;
    const u16*   wg  = WT + (bn + sr) * (size_t)K + sh;
    u16* al = &Al[sr * LDK + sh];
    u16* wl = &Wl[sr * LDK + sh];

    for (int k0 = 0; k0 < K; k0 += BK) {
        if (AF32) {
            float4 f0 = *(const float4*)(agf + k0);
            float4 f1 = *(const float4*)(agf + k0 + 4);
            float4 f2 = *(const float4*)(agf + k0 + 8);
            float4 f3 = *(const float4*)(agf + k0 + 12);
            u16 tmp[16];
            tmp[0]  = f2bf(f0.x); tmp[1]  = f2bf(f0.y); tmp[2]  = f2bf(f0.z); tmp[3]  = f2bf(f0.w);
            tmp[4]  = f2bf(f1.x); tmp[5]  = f2bf(f1.y); tmp[6]  = f2bf(f1.z); tmp[7]  = f2bf(f1.w);
            tmp[8]  = f2bf(f2.x); tmp[9]  = f2bf(f2.y); tmp[10] = f2bf(f2.z); tmp[11] = f2bf(f2.w);
            tmp[12] = f2bf(f3.x); tmp[13] = f2bf(f3.y); tmp[14] = f2bf(f3.z); tmp[15] = f2bf(f3.w);
            *(uint4*)(al)     = *(const uint4*)(tmp);
            *(uint4*)(al + 8) = *(const uint4*)(tmp + 8);
        } else {
            uint4 a0 = *(const uint4*)(agb + k0);
            uint4 a1 = *(const uint4*)(agb + k0 + 8);
            *(uint4*)(al)     = a0;
            *(uint4*)(al + 8) = a1;
        }
        uint4 w0 = *(const uint4*)(wg + k0);
        uint4 w1 = *(const uint4*)(wg + k0 + 8);
        *(uint4*)(wl)     = w0;
        *(uint4*)(wl + 8) = w1;
        __syncthreads();

        bf16x8 af[4], bfr[4];
#pragma unroll
        for (int mt = 0; mt < 4; mt++)
            af[mt] = *(const bf16x8*)&Al[(wm * 64 + mt * 16 + col) * LDK + qq * 8];
#pragma unroll
        for (int nt = 0; nt < 4; nt++)
            bfr[nt] = *(const bf16x8*)&Wl[(wn * 64 + nt * 16 + col) * LDK + qq * 8];
#pragma unroll
        for (int mt = 0; mt < 4; mt++)
#pragma unroll
            for (int nt = 0; nt < 4; nt++)
                acc[mt][nt] = __builtin_amdgcn_mfma_f32_16x16x32_bf16(
                    af[mt], bfr[nt], acc[mt][nt], 0, 0, 0);
        __syncthreads();
    }

    float bv[4];
#pragma unroll
    for (int nt = 0; nt < 4; nt++)
        bv[nt] = bias[bn + wn * 64 + nt * 16 + col];

#pragma unroll
    for (int mt = 0; mt < 4; mt++) {
#pragma unroll
        for (int nt = 0; nt < 4; nt++) {
#pragma unroll
            for (int r = 0; r < 4; r++) {
                float v = acc[mt][nt][r] + bv[nt];
                if (ACT == 1) v = 0.5f * v * (1.0f + erff(v * 0.70710678118654752f));
                size_t rg = bm + wm * 64 + mt * 16 + qq * 4 + r;
                C[rg * (size_t)N + bn + wn * 64 + nt * 16 + col] = f2bf(v);
            }
        }
    }
}

// ---------------------------------------------------------------- attention
// grid: (HEADS, TOK/4). Block handles 4 query rows of one (b,h). bf16 Q/K/V, fp32 bias/math.
__global__ __launch_bounds__(256) void attn_kernel(
    const u16* __restrict__ Q, const u16* __restrict__ K,
    const u16* __restrict__ V, const float* __restrict__ ab,
    u16* __restrict__ O)
{
    __shared__ float S[4][SEQ];
    __shared__ float q[4][HD];
    __shared__ float pbuf[4][HD];
    __shared__ float red[4];
    __shared__ float invs[4];

    const int tid = threadIdx.x;
    const int h = blockIdx.x;
    const int tile = blockIdx.y;          // 0..1023
    const int b = tile >> 9;              // 512 tiles per batch
    const int n0 = (tile & 511) * 4;      // query row base within sequence

    {
        int i = tid >> 6, d = tid & 63;
        q[i][d] = bf2f(Q[((size_t)(b * SEQ + n0 + i)) * EMB + h * HD + d]);
    }
    __syncthreads();

    // pass 1: scores
    for (int jj = tid; jj < SEQ; jj += 256) {
        const u16* kp = K + ((size_t)(b * SEQ + jj)) * EMB + h * HD;
        float kreg[64];
#pragma unroll
        for (int d0 = 0; d0 < 64; d0++) kreg[d0] = bf2f(kp[d0]);
#pragma unroll
        for (int i = 0; i < 4; i++) {
            float acc = 0.0f;
#pragma unroll
            for (int d0 = 0; d0 < 64; d0++) acc += q[i][d0] * kreg[d0];
            S[i][jj] = acc * 0.125f + ab[(size_t)(n0 + i) * SEQ + jj];
        }
    }
    __syncthreads();

    // softmax per row
    for (int i = 0; i < 4; i++) {
        float m = -1e30f;
        for (int j = tid; j < SEQ; j += 256) m = fmaxf(m, S[i][j]);
#pragma unroll
        for (int o = 32; o > 0; o >>= 1) m = fmaxf(m, __shfl_down(m, o));
        if ((tid & 63) == 0) red[tid >> 6] = m;
        __syncthreads();
        m = fmaxf(fmaxf(red[0], red[1]), fmaxf(red[2], red[3]));
        __syncthreads();

        float sum = 0.0f;
        for (int j = tid; j < SEQ; j += 256) {
            float e = __expf(S[i][j] - m);
            S[i][j] = e;
            sum += e;
        }
#pragma unroll
        for (int o = 32; o > 0; o >>= 1) sum += __shfl_down(sum, o);
        if ((tid & 63) == 0) red[tid >> 6] = sum;
        __syncthreads();
        sum = red[0] + red[1] + red[2] + red[3];
        if (tid == 0) invs[i] = 1.0f / sum;
        __syncthreads();
    }

    // pass 2: PV
    const int d = tid & 63;
    const int g = tid >> 6;   // 0..3
    float acc0 = 0, acc1 = 0, acc2 = 0, acc3 = 0;
    for (int j = g; j < SEQ; j += 4) {
        float v = bf2f(V[((size_t)(b * SEQ + j)) * EMB + h * HD + d]);
        acc0 += S[0][j] * v;
        acc1 += S[1][j] * v;
        acc2 += S[2][j] * v;
        acc3 += S[3][j] * v;
    }
    float accs[4] = {acc0, acc1, acc2, acc3};
#pragma unroll
    for (int i = 0; i < 4; i++) {
        pbuf[g][d] = accs[i];
        __syncthreads();
        if (g == 0) {
            float o = (pbuf[0][d] + pbuf[1][d] + pbuf[2][d] + pbuf[3][d]) * invs[i];
            O[((size_t)(b * SEQ + n0 + i)) * EMB + h * HD + d] = f2bf(o);
        }
        __syncthreads();
    }
}

// ---------------------------------------------------------------- residual + LayerNorm
// one block per token row; out = LN(A[row] + R[row]).
// AF32: A is fp32 (else bf16). R always bf16. OUTF32: write fp32 (else bf16).
template <int AF32, int OUTF32>
__global__ __launch_bounds__(256) void ln_kernel(
    const void* __restrict__ A, const u16* __restrict__ R,
    const float* __restrict__ w, const float* __restrict__ bb,
    void* __restrict__ out)
{
    __shared__ float r1[4], r2[4];
    const int tid = threadIdx.x;
    const size_t row = blockIdx.x;

    float v[4];
    float s = 0.0f, s2 = 0.0f;
#pragma unroll
    for (int i = 0; i < 4; i++) {
        int c = tid + i * 256;
        float a = AF32 ? ((const float*)A)[row * EMB + c]
                       : bf2f(((const u16*)A)[row * EMB + c]);
        float t = a + bf2f(R[row * EMB + c]);
        v[i] = t;
        s += t; s2 += t * t;
    }
#pragma unroll
    for (int o = 32; o > 0; o >>= 1) {
        s  += __shfl_down(s, o);
        s2 += __shfl_down(s2, o);
    }
    if ((tid & 63) == 0) { r1[tid >> 6] = s; r2[tid >> 6] = s2; }
    __syncthreads();
    s  = r1[0] + r1[1] + r1[2] + r1[3];
    s2 = r2[0] + r2[1] + r2[2] + r2[3];

    float mu = s * (1.0f / EMB);
    float var = s2 * (1.0f / EMB) - mu * mu;
    float rs = rsqrtf(var + 1e-5f);

#pragma unroll
    for (int i = 0; i < 4; i++) {
        int c = tid + i * 256;
        float y = (v[i] - mu) * rs * w[c] + bb[c];
        if (OUTF32) ((float*)out)[row * EMB + c] = y;
        else        ((u16*)out)[row * EMB + c] = f2bf(y);
    }
}

// ---------------------------------------------------------------- launch
extern "C" void kernel_launch(void* const* d_in, const int* in_sizes, int n_in,
                              void* d_out, int out_size, void* d_ws, size_t ws_size,
                              hipStream_t stream)
{
    const float* x    = (const float*)d_in[0];
    const float* ab   = (const float*)d_in[1];
    const float* Wq   = (const float*)d_in[2];
    const float* bq   = (const float*)d_in[3];
    const float* WaK  = (const float*)d_in[4];
    const float* baK  = (const float*)d_in[5];
    const float* WbK  = (const float*)d_in[6];
    const float* bbK  = (const float*)d_in[7];
    const float* WaV  = (const float*)d_in[8];
    const float* baV  = (const float*)d_in[9];
    const float* WbV  = (const float*)d_in[10];
    const float* bbV  = (const float*)d_in[11];
    const float* Wo   = (const float*)d_in[12];
    const float* bo   = (const float*)d_in[13];
    const float* W1   = (const float*)d_in[14];
    const float* b1   = (const float*)d_in[15];
    const float* W2   = (const float*)d_in[16];
    const float* b2   = (const float*)d_in[17];
    const float* ln1w = (const float*)d_in[18];
    const float* ln1b = (const float*)d_in[19];
    const float* ln2w = (const float*)d_in[20];
    const float* ln2b = (const float*)d_in[21];

    u16* w = (u16*)d_ws;
    size_t o = 0;
    u16* WqT  = w + o; o += (size_t)EMB * EMB;     // 1Mi
    u16* WaKT = w + o; o += (size_t)EMB * LATD;    // 256Ki
    u16* WbKT = w + o; o += (size_t)LATD * EMB;
    u16* WaVT = w + o; o += (size_t)EMB * LATD;
    u16* WbVT = w + o; o += (size_t)LATD * EMB;
    u16* WoT  = w + o; o += (size_t)EMB * EMB;
    u16* W1T  = w + o; o += (size_t)EMB * FFND;    // 4Mi
    u16* W2T  = w + o; o += (size_t)FFND * EMB;    // 4Mi
    u16* Qb   = w + o; o += (size_t)TOK * EMB;     // 4Mi
    u16* Kb   = w + o; o += (size_t)TOK * EMB;
    u16* Vb   = w + o; o += (size_t)TOK * EMB;
    u16* aOb  = w + o; o += (size_t)TOK * EMB;
    u16* projb= w + o; o += (size_t)TOK * EMB;
    u16* hb   = w + o; o += (size_t)TOK * EMB;
    // reuse (non-overlapping lifetimes):
    u16* Ka = projb;                          // dead before proj written
    u16* Va = projb + (size_t)TOK * LATD;
    u16* f1 = Qb;                             // spans Qb..aOb = TOK*FFND
    u16* f2 = projb;                          // proj dead after ln1

    dim3 blk(256);

    // weight transposes + fp32->bf16 convert
    transpose_cvt_kernel<<<dim3(EMB / 32, EMB / 32), blk, 0, stream>>>(Wq, WqT, EMB, EMB);
    transpose_cvt_kernel<<<dim3(LATD / 32, EMB / 32), blk, 0, stream>>>(WaK, WaKT, EMB, LATD);
    transpose_cvt_kernel<<<dim3(EMB / 32, LATD / 32), blk, 0, stream>>>(WbK, WbKT, LATD, EMB);
    transpose_cvt_kernel<<<dim3(LATD / 32, EMB / 32), blk, 0, stream>>>(WaV, WaVT, EMB, LATD);
    transpose_cvt_kernel<<<dim3(EMB / 32, LATD / 32), blk, 0, stream>>>(WbV, WbVT, LATD, EMB);
    transpose_cvt_kernel<<<dim3(EMB / 32, EMB / 32), blk, 0, stream>>>(Wo, WoT, EMB, EMB);
    transpose_cvt_kernel<<<dim3(FFND / 32, EMB / 32), blk, 0, stream>>>(W1, W1T, EMB, FFND);
    transpose_cvt_kernel<<<dim3(EMB / 32, FFND / 32), blk, 0, stream>>>(W2, W2T, FFND, EMB);

    // Q = x @ Wq + bq
    gemm_bt_kernel<0,1><<<dim3(EMB / BN, TOK / BM), blk, 0, stream>>>(x, WqT, bq, Qb, TOK, EMB, EMB);
    // K = (x @ WaK + baK) @ WbK + bbK
    gemm_bt_kernel<0,1><<<dim3(LATD / BN, TOK / BM), blk, 0, stream>>>(x, WaKT, baK, Ka, TOK, EMB, LATD);
    gemm_bt_kernel<0,0><<<dim3(EMB / BN, TOK / BM), blk, 0, stream>>>(Ka, WbKT, bbK, Kb, TOK, LATD, EMB);
    // V = (x @ WaV + baV) @ WbV + bbV
    gemm_bt_kernel<0,1><<<dim3(LATD / BN, TOK / BM), blk, 0, stream>>>(x, WaVT, baV, Va, TOK, EMB, LATD);
    gemm_bt_kernel<0,0><<<dim3(EMB / BN, TOK / BM), blk, 0, stream>>>(Va, WbVT, bbV, Vb, TOK, LATD, EMB);

    // attention -> aOb
    attn_kernel<<<dim3(HEADS, TOK / 4), blk, 0, stream>>>(Qb, Kb, Vb, ab, aOb);

    // proj = aO @ Wo + bo
    gemm_bt_kernel<0,0><<<dim3(EMB / BN, TOK / BM), blk, 0, stream>>>(aOb, WoT, bo, projb, TOK, EMB, EMB);

    // h = LN(x + proj) -> bf16 hb
    ln_kernel<1,0><<<dim3(TOK), blk, 0, stream>>>(x, projb, ln1w, ln1b, hb);

    // f1 = gelu(h @ W1 + b1) ; f2 = f1 @ W2 + b2
    gemm_bt_kernel<1,0><<<dim3(FFND / BN, TOK / BM), blk, 0, stream>>>(hb, W1T, b1, f1, TOK, EMB, FFND);
    gemm_bt_kernel<0,0><<<dim3(EMB / BN, TOK / BM), blk, 0, stream>>>(f1, W2T, b2, f2, TOK, FFND, EMB);

    // out = LN(h + f2) -> fp32 d_out
    ln_kernel<0,1><<<dim3(TOK), blk, 0, stream>>>(hb, f2, ln2w, ln2b, (float*)d_out);
}

// Round 4
// 593.784 us; speedup vs baseline: 9.6775x; 9.6775x over previous
//
#include <hip/hip_runtime.h>
#include <hip/hip_bf16.h>
#include <math.h>

typedef unsigned short u16;
typedef short bf16x8 __attribute__((ext_vector_type(8)));
typedef float f32x4 __attribute__((ext_vector_type(4)));

#define EMB   1024
#define HEADS 16
#define HD    64
#define LATD  256
#define FFND  4096
#define BATCH 2
#define SEQ   2048
#define TOK   (BATCH*SEQ)   // 4096

__device__ __forceinline__ float bf2f(u16 u) {
    union { unsigned int i; float f; } x; x.i = ((unsigned int)u) << 16; return x.f;
}
__device__ __forceinline__ u16 f2bf(float f) {
    union { float f; unsigned int i; } x; x.f = f;
    unsigned int i = x.i;
    unsigned int lsb = (i >> 16) & 1u;
    i += 0x7fffu + lsb;       // round-to-nearest-even
    return (u16)(i >> 16);
}

// ---------------------------------------------------------------- transpose + fp32->bf16 convert
// out[N][K] (bf16) = in[K][N] (fp32). 32x32 tiles, 256 threads.
__global__ __launch_bounds__(256) void transpose_cvt_kernel(
    const float* __restrict__ in, u16* __restrict__ out, int K, int N)
{
    __shared__ u16 t[32][33];
    const int bx = blockIdx.x * 32;  // n base
    const int by = blockIdx.y * 32;  // k base
    const int tx = threadIdx.x & 31;
    const int ty = threadIdx.x >> 5; // 0..7
#pragma unroll
    for (int i = 0; i < 32; i += 8)
        t[ty + i][tx] = f2bf(in[(size_t)(by + ty + i) * N + bx + tx]);
    __syncthreads();
#pragma unroll
    for (int i = 0; i < 32; i += 8)
        out[(size_t)(bx + ty + i) * K + by + tx] = t[tx][ty + i];
}

// ---------------------------------------------------------------- MFMA GEMM (B^T form)
// C[M,N] bf16 = A[M,K] @ W[K,N] + bias[N](fp32), W pre-transposed+converted: WT[N][K] bf16.
// A is fp32 (AF32=1) or bf16 (AF32=0). 128x128 tile, 4 waves, 4x4 16x16x32 MFMA, BK=32.
#define BM 128
#define BN 128
#define BK 32
#define LDK 40   // padded LDS K-stride (elements)

template <int ACT, int AF32>
__global__ __launch_bounds__(256, 2) void gemm_bt_kernel(
    const void* __restrict__ A, const u16* __restrict__ WT,
    const float* __restrict__ bias, u16* __restrict__ C,
    int M, int K, int N)
{
    __shared__ __align__(16) u16 Al[BM * LDK];
    __shared__ __align__(16) u16 Wl[BN * LDK];

    const int tid  = threadIdx.x;
    const int lane = tid & 63;
    const int wid  = tid >> 6;
    const int wm = wid >> 1, wn = wid & 1;
    const int col = lane & 15, qq = lane >> 4;
    const size_t bm = (size_t)blockIdx.y * BM;
    const size_t bn = (size_t)blockIdx.x * BN;

    const int sr = tid >> 1;         // staging row 0..127
    const int sh = (tid & 1) * 16;   // element offset 0/16 within BK

    f32x4 acc[4][4];
#pragma unroll
    for (int mt = 0; mt < 4; mt++)
#pragma unroll
        for (int nt = 0; nt < 4; nt++) acc[mt][nt] = (f32x4){0.f, 0.f, 0.f, 0.f};

    const float* agf = (const float*)A + (bm + sr) * (size_t)K + sh;
    const u16*   agb = (const u16*)A   + (bm + sr) * (size_t)K + sh;
    const u16*   wg  = WT + (bn + sr) * (size_t)K + sh;
    u16* al = &Al[sr * LDK + sh];
    u16* wl = &Wl[sr * LDK + sh];

    for (int k0 = 0; k0 < K; k0 += BK) {
        if (AF32) {
            float4 f0 = *(const float4*)(agf + k0);
            float4 f1 = *(const float4*)(agf + k0 + 4);
            float4 f2 = *(const float4*)(agf + k0 + 8);
            float4 f3 = *(const float4*)(agf + k0 + 12);
            u16 tmp[16];
            tmp[0]  = f2bf(f0.x); tmp[1]  = f2bf(f0.y); tmp[2]  = f2bf(f0.z); tmp[3]  = f2bf(f0.w);
            tmp[4]  = f2bf(f1.x); tmp[5]  = f2bf(f1.y); tmp[6]  = f2bf(f1.z); tmp[7]  = f2bf(f1.w);
            tmp[8]  = f2bf(f2.x); tmp[9]  = f2bf(f2.y); tmp[10] = f2bf(f2.z); tmp[11] = f2bf(f2.w);
            tmp[12] = f2bf(f3.x); tmp[13] = f2bf(f3.y); tmp[14] = f2bf(f3.z); tmp[15] = f2bf(f3.w);
            *(uint4*)(al)     = *(const uint4*)(tmp);
            *(uint4*)(al + 8) = *(const uint4*)(tmp + 8);
        } else {
            uint4 a0 = *(const uint4*)(agb + k0);
            uint4 a1 = *(const uint4*)(agb + k0 + 8);
            *(uint4*)(al)     = a0;
            *(uint4*)(al + 8) = a1;
        }
        uint4 w0 = *(const uint4*)(wg + k0);
        uint4 w1 = *(const uint4*)(wg + k0 + 8);
        *(uint4*)(wl)     = w0;
        *(uint4*)(wl + 8) = w1;
        __syncthreads();

        bf16x8 af[4], bfr[4];
#pragma unroll
        for (int mt = 0; mt < 4; mt++)
            af[mt] = *(const bf16x8*)&Al[(wm * 64 + mt * 16 + col) * LDK + qq * 8];
#pragma unroll
        for (int nt = 0; nt < 4; nt++)
            bfr[nt] = *(const bf16x8*)&Wl[(wn * 64 + nt * 16 + col) * LDK + qq * 8];
#pragma unroll
        for (int mt = 0; mt < 4; mt++)
#pragma unroll
            for (int nt = 0; nt < 4; nt++)
                acc[mt][nt] = __builtin_amdgcn_mfma_f32_16x16x32_bf16(
                    af[mt], bfr[nt], acc[mt][nt], 0, 0, 0);
        __syncthreads();
    }

    float bv[4];
#pragma unroll
    for (int nt = 0; nt < 4; nt++)
        bv[nt] = bias[bn + wn * 64 + nt * 16 + col];

#pragma unroll
    for (int mt = 0; mt < 4; mt++) {
#pragma unroll
        for (int nt = 0; nt < 4; nt++) {
#pragma unroll
            for (int r = 0; r < 4; r++) {
                float v = acc[mt][nt][r] + bv[nt];
                if (ACT == 1) v = 0.5f * v * (1.0f + erff(v * 0.70710678118654752f));
                size_t rg = bm + wm * 64 + mt * 16 + qq * 4 + r;
                C[rg * (size_t)N + bn + wn * 64 + nt * 16 + col] = f2bf(v);
            }
        }
    }
}

// ---------------------------------------------------------------- flash attention (MFMA)
// grid (SEQ/BQ, BATCH*HEADS); block = 256 threads = 4 waves; wave w owns q rows [32w,32w+32).
// Per 128-key tile: S=(Q/8)K^T via MFMA, +bias, online softmax, P->LDS (aliases K buf), PV via MFMA.
#define BQ  128
#define BKV 128
#define LDQ 72    // K/Q LDS row stride (64+8)
#define LDP 136   // P/Vt LDS row stride (128+8)

__global__ __launch_bounds__(256) void fattn_kernel(
    const u16* __restrict__ Q, const u16* __restrict__ K,
    const u16* __restrict__ V, const float* __restrict__ ab,
    u16* __restrict__ O)
{
    __shared__ __align__(16) u16 Qs[BQ * LDQ];     // 18,432 B
    __shared__ __align__(16) u16 KP[BQ * LDP];     // 34,816 B (Ks stride LDQ / Ps stride LDP)
    __shared__ __align__(16) u16 Vt[HD * LDP];     // 17,408 B

    const int tid = threadIdx.x;
    const int lane = tid & 63;
    const int w = tid >> 6;
    const int col = lane & 15, qq = lane >> 4;
    const int qt = blockIdx.x;
    const int b = blockIdx.y >> 4, h = blockIdx.y & 15;
    const size_t tok0 = (size_t)b * SEQ + (size_t)qt * BQ;
    const int qrow0 = qt * BQ;

    // load Q tile, pre-scaled by 1/8 (exact: power of 2)
    for (int c = tid; c < BQ * 8; c += 256) {
        int qr = c >> 3, d0 = (c & 7) * 8;
        uint4 t = *(const uint4*)(Q + (tok0 + qr) * EMB + h * HD + d0);
        u16 e[8]; *(uint4*)e = t;
#pragma unroll
        for (int i = 0; i < 8; i++) e[i] = f2bf(bf2f(e[i]) * 0.125f);
        *(uint4*)&Qs[qr * LDQ + d0] = *(const uint4*)e;
    }

    float m_st[2][4], l_st[2][4];
    f32x4 o_acc[2][4];
#pragma unroll
    for (int mt = 0; mt < 2; mt++)
#pragma unroll
        for (int r = 0; r < 4; r++) { m_st[mt][r] = -1e30f; l_st[mt][r] = 0.f; }
#pragma unroll
    for (int mt = 0; mt < 2; mt++)
#pragma unroll
        for (int dt = 0; dt < 4; dt++) o_acc[mt][dt] = (f32x4){0.f, 0.f, 0.f, 0.f};

    for (int kv0 = 0; kv0 < SEQ; kv0 += BKV) {
        // stage K tile [128][64] -> KP (stride LDQ)
        for (int c = tid; c < BKV * 8; c += 256) {
            int kr = c >> 3, d0 = (c & 7) * 8;
            *(uint4*)&KP[kr * LDQ + d0] =
                *(const uint4*)(K + ((size_t)b * SEQ + kv0 + kr) * EMB + h * HD + d0);
        }
        // stage V tile transposed -> Vt[d][j] (stride LDP)
        for (int c = tid; c < BKV * 8; c += 256) {
            int j = c & 127, d0 = (c >> 7) * 8;
            uint4 t = *(const uint4*)(V + ((size_t)b * SEQ + kv0 + j) * EMB + h * HD + d0);
            u16 e[8]; *(uint4*)e = t;
#pragma unroll
            for (int i = 0; i < 8; i++) Vt[(d0 + i) * LDP + j] = e[i];
        }
        __syncthreads();

        // S = (Q/8) @ K^T   (2 m-tiles x 8 n-tiles x 2 k-steps)
        f32x4 s[2][8];
        bf16x8 aq[2][2];
#pragma unroll
        for (int mt = 0; mt < 2; mt++)
#pragma unroll
            for (int kk = 0; kk < 2; kk++)
                aq[mt][kk] = *(const bf16x8*)&Qs[(w * 32 + mt * 16 + col) * LDQ + kk * 32 + qq * 8];
#pragma unroll
        for (int nt = 0; nt < 8; nt++) {
            bf16x8 bk0 = *(const bf16x8*)&KP[(nt * 16 + col) * LDQ + qq * 8];
            bf16x8 bk1 = *(const bf16x8*)&KP[(nt * 16 + col) * LDQ + 32 + qq * 8];
#pragma unroll
            for (int mt = 0; mt < 2; mt++) {
                f32x4 t = (f32x4){0.f, 0.f, 0.f, 0.f};
                t = __builtin_amdgcn_mfma_f32_16x16x32_bf16(aq[mt][0], bk0, t, 0, 0, 0);
                t = __builtin_amdgcn_mfma_f32_16x16x32_bf16(aq[mt][1], bk1, t, 0, 0, 0);
                s[mt][nt] = t;
            }
        }

        // + attn_bias (fp32, direct from global; C-layout row=qq*4+r, col=lane&15)
#pragma unroll
        for (int mt = 0; mt < 2; mt++)
#pragma unroll
            for (int nt = 0; nt < 8; nt++)
#pragma unroll
                for (int r = 0; r < 4; r++)
                    s[mt][nt][r] += ab[(size_t)(qrow0 + w * 32 + mt * 16 + qq * 4 + r) * SEQ
                                       + kv0 + nt * 16 + col];

        // online softmax
        float alpha[2][4];
        float p[2][8][4];
#pragma unroll
        for (int mt = 0; mt < 2; mt++) {
#pragma unroll
            for (int r = 0; r < 4; r++) {
                float tm = s[mt][0][r];
#pragma unroll
                for (int nt = 1; nt < 8; nt++) tm = fmaxf(tm, s[mt][nt][r]);
#pragma unroll
                for (int msk = 1; msk < 16; msk <<= 1) tm = fmaxf(tm, __shfl_xor(tm, msk));
                float mnew = fmaxf(m_st[mt][r], tm);
                float al = __expf(m_st[mt][r] - mnew);
                m_st[mt][r] = mnew;
                alpha[mt][r] = al;
                float rs = 0.f;
#pragma unroll
                for (int nt = 0; nt < 8; nt++) {
                    float e = __expf(s[mt][nt][r] - mnew);
                    p[mt][nt][r] = e;
                    rs += e;
                }
#pragma unroll
                for (int msk = 1; msk < 16; msk <<= 1) rs += __shfl_xor(rs, msk);
                l_st[mt][r] = l_st[mt][r] * al + rs;
            }
        }
#pragma unroll
        for (int mt = 0; mt < 2; mt++)
#pragma unroll
            for (int dt = 0; dt < 4; dt++)
#pragma unroll
                for (int r = 0; r < 4; r++)
                    o_acc[mt][dt][r] *= alpha[mt][r];

        __syncthreads();   // all waves finished reading Ks
        // write P (bf16) over the K region, stride LDP (C-layout -> A-layout transform)
#pragma unroll
        for (int mt = 0; mt < 2; mt++)
#pragma unroll
            for (int nt = 0; nt < 8; nt++)
#pragma unroll
                for (int r = 0; r < 4; r++)
                    KP[(w * 32 + mt * 16 + qq * 4 + r) * LDP + nt * 16 + col] = f2bf(p[mt][nt][r]);
        __syncthreads();

        // O += P @ V   (k = 128 keys, 4 k-steps; B operand = Vt[d][j])
#pragma unroll
        for (int kk = 0; kk < 4; kk++) {
            bf16x8 ap[2];
#pragma unroll
            for (int mt = 0; mt < 2; mt++)
                ap[mt] = *(const bf16x8*)&KP[(w * 32 + mt * 16 + col) * LDP + kk * 32 + qq * 8];
#pragma unroll
            for (int dt = 0; dt < 4; dt++) {
                bf16x8 bv = *(const bf16x8*)&Vt[(dt * 16 + col) * LDP + kk * 32 + qq * 8];
#pragma unroll
                for (int mt = 0; mt < 2; mt++)
                    o_acc[mt][dt] = __builtin_amdgcn_mfma_f32_16x16x32_bf16(
                        ap[mt], bv, o_acc[mt][dt], 0, 0, 0);
            }
        }
        __syncthreads();   // before next tile's staging overwrites KP/Vt
    }

    // epilogue: O / l
#pragma unroll
    for (int mt = 0; mt < 2; mt++) {
#pragma unroll
        for (int r = 0; r < 4; r++) {
            float inv = 1.0f / l_st[mt][r];
#pragma unroll
            for (int dt = 0; dt < 4; dt++)
                O[(tok0 + w * 32 + mt * 16 + qq * 4 + r) * EMB + h * HD + dt * 16 + col]
                    = f2bf(o_acc[mt][dt][r] * inv);
        }
    }
}

// ---------------------------------------------------------------- residual + LayerNorm
// one block per token row; out = LN(A[row] + R[row]).
// AF32: A is fp32 (else bf16). R always bf16. OUTF32: write fp32 (else bf16).
template <int AF32, int OUTF32>
__global__ __launch_bounds__(256) void ln_kernel(
    const void* __restrict__ A, const u16* __restrict__ R,
    const float* __restrict__ w, const float* __restrict__ bb,
    void* __restrict__ out)
{
    __shared__ float r1[4], r2[4];
    const int tid = threadIdx.x;
    const size_t row = blockIdx.x;

    float v[4];
    float s = 0.0f, s2 = 0.0f;
#pragma unroll
    for (int i = 0; i < 4; i++) {
        int c = tid + i * 256;
        float a = AF32 ? ((const float*)A)[row * EMB + c]
                       : bf2f(((const u16*)A)[row * EMB + c]);
        float t = a + bf2f(R[row * EMB + c]);
        v[i] = t;
        s += t; s2 += t * t;
    }
#pragma unroll
    for (int o = 32; o > 0; o >>= 1) {
        s  += __shfl_down(s, o);
        s2 += __shfl_down(s2, o);
    }
    if ((tid & 63) == 0) { r1[tid >> 6] = s; r2[tid >> 6] = s2; }
    __syncthreads();
    s  = r1[0] + r1[1] + r1[2] + r1[3];
    s2 = r2[0] + r2[1] + r2[2] + r2[3];

    float mu = s * (1.0f / EMB);
    float var = s2 * (1.0f / EMB) - mu * mu;
    float rs = rsqrtf(var + 1e-5f);

#pragma unroll
    for (int i = 0; i < 4; i++) {
        int c = tid + i * 256;
        float y = (v[i] - mu) * rs * w[c] + bb[c];
        if (OUTF32) ((float*)out)[row * EMB + c] = y;
        else        ((u16*)out)[row * EMB + c] = f2bf(y);
    }
}

// ---------------------------------------------------------------- launch
extern "C" void kernel_launch(void* const* d_in, const int* in_sizes, int n_in,
                              void* d_out, int out_size, void* d_ws, size_t ws_size,
                              hipStream_t stream)
{
    const float* x    = (const float*)d_in[0];
    const float* ab   = (const float*)d_in[1];
    const float* Wq   = (const float*)d_in[2];
    const float* bq   = (const float*)d_in[3];
    const float* WaK  = (const float*)d_in[4];
    const float* baK  = (const float*)d_in[5];
    const float* WbK  = (const float*)d_in[6];
    const float* bbK  = (const float*)d_in[7];
    const float* WaV  = (const float*)d_in[8];
    const float* baV  = (const float*)d_in[9];
    const float* WbV  = (const float*)d_in[10];
    const float* bbV  = (const float*)d_in[11];
    const float* Wo   = (const float*)d_in[12];
    const float* bo   = (const float*)d_in[13];
    const float* W1   = (const float*)d_in[14];
    const float* b1   = (const float*)d_in[15];
    const float* W2   = (const float*)d_in[16];
    const float* b2   = (const float*)d_in[17];
    const float* ln1w = (const float*)d_in[18];
    const float* ln1b = (const float*)d_in[19];
    const float* ln2w = (const float*)d_in[20];
    const float* ln2b = (const float*)d_in[21];

    u16* w = (u16*)d_ws;
    size_t o = 0;
    u16* WqT  = w + o; o += (size_t)EMB * EMB;     // 1Mi
    u16* WaKT = w + o; o += (size_t)EMB * LATD;    // 256Ki
    u16* WbKT = w + o; o += (size_t)LATD * EMB;
    u16* WaVT = w + o; o += (size_t)EMB * LATD;
    u16* WbVT = w + o; o += (size_t)LATD * EMB;
    u16* WoT  = w + o; o += (size_t)EMB * EMB;
    u16* W1T  = w + o; o += (size_t)EMB * FFND;    // 4Mi
    u16* W2T  = w + o; o += (size_t)FFND * EMB;    // 4Mi
    u16* Qb   = w + o; o += (size_t)TOK * EMB;     // 4Mi
    u16* Kb   = w + o; o += (size_t)TOK * EMB;
    u16* Vb   = w + o; o += (size_t)TOK * EMB;
    u16* aOb  = w + o; o += (size_t)TOK * EMB;
    u16* projb= w + o; o += (size_t)TOK * EMB;
    u16* hb   = w + o; o += (size_t)TOK * EMB;
    // reuse (non-overlapping lifetimes):
    u16* Ka = projb;                          // dead before proj written
    u16* Va = projb + (size_t)TOK * LATD;
    u16* f1 = Qb;                             // spans Qb..aOb = TOK*FFND
    u16* f2 = projb;                          // proj dead after ln1

    dim3 blk(256);

    // weight transposes + fp32->bf16 convert
    transpose_cvt_kernel<<<dim3(EMB / 32, EMB / 32), blk, 0, stream>>>(Wq, WqT, EMB, EMB);
    transpose_cvt_kernel<<<dim3(LATD / 32, EMB / 32), blk, 0, stream>>>(WaK, WaKT, EMB, LATD);
    transpose_cvt_kernel<<<dim3(EMB / 32, LATD / 32), blk, 0, stream>>>(WbK, WbKT, LATD, EMB);
    transpose_cvt_kernel<<<dim3(LATD / 32, EMB / 32), blk, 0, stream>>>(WaV, WaVT, EMB, LATD);
    transpose_cvt_kernel<<<dim3(EMB / 32, LATD / 32), blk, 0, stream>>>(WbV, WbVT, LATD, EMB);
    transpose_cvt_kernel<<<dim3(EMB / 32, EMB / 32), blk, 0, stream>>>(Wo, WoT, EMB, EMB);
    transpose_cvt_kernel<<<dim3(FFND / 32, EMB / 32), blk, 0, stream>>>(W1, W1T, EMB, FFND);
    transpose_cvt_kernel<<<dim3(EMB / 32, FFND / 32), blk, 0, stream>>>(W2, W2T, FFND, EMB);

    // Q = x @ Wq + bq
    gemm_bt_kernel<0,1><<<dim3(EMB / BN, TOK / BM), blk, 0, stream>>>(x, WqT, bq, Qb, TOK, EMB, EMB);
    // K = (x @ WaK + baK) @ WbK + bbK
    gemm_bt_kernel<0,1><<<dim3(LATD / BN, TOK / BM), blk, 0, stream>>>(x, WaKT, baK, Ka, TOK, EMB, LATD);
    gemm_bt_kernel<0,0><<<dim3(EMB / BN, TOK / BM), blk, 0, stream>>>(Ka, WbKT, bbK, Kb, TOK, LATD, EMB);
    // V = (x @ WaV + baV) @ WbV + bbV
    gemm_bt_kernel<0,1><<<dim3(LATD / BN, TOK / BM), blk, 0, stream>>>(x, WaVT, baV, Va, TOK, EMB, LATD);
    gemm_bt_kernel<0,0><<<dim3(EMB / BN, TOK / BM), blk, 0, stream>>>(Va, WbVT, bbV, Vb, TOK, LATD, EMB);

    // flash attention -> aOb
    fattn_kernel<<<dim3(SEQ / BQ, BATCH * HEADS), blk, 0, stream>>>(Qb, Kb, Vb, ab, aOb);

    // proj = aO @ Wo + bo
    gemm_bt_kernel<0,0><<<dim3(EMB / BN, TOK / BM), blk, 0, stream>>>(aOb, WoT, bo, projb, TOK, EMB, EMB);

    // h = LN(x + proj) -> bf16 hb
    ln_kernel<1,0><<<dim3(TOK), blk, 0, stream>>>(x, projb, ln1w, ln1b, hb);

    // f1 = gelu(h @ W1 + b1) ; f2 = f1 @ W2 + b2
    gemm_bt_kernel<1,0><<<dim3(FFND / BN, TOK / BM), blk, 0, stream>>>(hb, W1T, b1, f1, TOK, EMB, FFND);
    gemm_bt_kernel<0,0><<<dim3(EMB / BN, TOK / BM), blk, 0, stream>>>(f1, W2T, b2, f2, TOK, FFND, EMB);

    // out = LN(h + f2) -> fp32 d_out
    ln_kernel<0,1><<<dim3(TOK), blk, 0, stream>>>(hb, f2, ln2w, ln2b, (float*)d_out);
}

// Round 5
// 524.716 us; speedup vs baseline: 10.9513x; 1.1316x over previous
//
#include <hip/hip_runtime.h>
#include <hip/hip_bf16.h>
#include <math.h>

typedef unsigned short u16;
typedef short bf16x8 __attribute__((ext_vector_type(8)));
typedef float f32x4 __attribute__((ext_vector_type(4)));

#define EMB   1024
#define HEADS 16
#define HD    64
#define LATD  256
#define FFND  4096
#define BATCH 2
#define SEQ   2048
#define TOK   (BATCH*SEQ)   // 4096

__device__ __forceinline__ float bf2f(u16 u) {
    union { unsigned int i; float f; } x; x.i = ((unsigned int)u) << 16; return x.f;
}
__device__ __forceinline__ u16 f2bf(float f) {
    union { float f; unsigned int i; } x; x.f = f;
    unsigned int i = x.i;
    unsigned int lsb = (i >> 16) & 1u;
    i += 0x7fffu + lsb;       // round-to-nearest-even
    return (u16)(i >> 16);
}
__device__ __forceinline__ void gld16(const u16* g, u16* l) {
    __builtin_amdgcn_global_load_lds(
        (const __attribute__((address_space(1))) void*)g,
        (__attribute__((address_space(3))) void*)l, 16, 0, 0);
}

// ---------------------------------------------------------------- fp32 -> bf16 convert
__global__ __launch_bounds__(256) void cvt_f32_bf16_kernel(
    const float* __restrict__ in, u16* __restrict__ out, int n8)
{
    int i = blockIdx.x * 256 + threadIdx.x;
    int stride = gridDim.x * 256;
    for (; i < n8; i += stride) {
        float4 f0 = *(const float4*)(in + (size_t)i * 8);
        float4 f1 = *(const float4*)(in + (size_t)i * 8 + 4);
        u16 e[8];
        e[0] = f2bf(f0.x); e[1] = f2bf(f0.y); e[2] = f2bf(f0.z); e[3] = f2bf(f0.w);
        e[4] = f2bf(f1.x); e[5] = f2bf(f1.y); e[6] = f2bf(f1.z); e[7] = f2bf(f1.w);
        *(uint4*)(out + (size_t)i * 8) = *(const uint4*)e;
    }
}

// ---------------------------------------------------------------- concat 2 bias vectors (256 each)
__global__ __launch_bounds__(256) void concat_bias_kernel(
    const float* __restrict__ a, const float* __restrict__ b, float* __restrict__ out)
{
    int i = blockIdx.x * 256 + threadIdx.x;   // 0..511
    out[i] = (i < 256) ? a[i] : b[i - 256];
}

// ---------------------------------------------------------------- transpose + fp32->bf16 convert
// out[N][K] (bf16) = in[K][N] (fp32). 32x32 tiles, 256 threads.
__global__ __launch_bounds__(256) void transpose_cvt_kernel(
    const float* __restrict__ in, u16* __restrict__ out, int K, int N)
{
    __shared__ u16 t[32][33];
    const int bx = blockIdx.x * 32;  // n base
    const int by = blockIdx.y * 32;  // k base
    const int tx = threadIdx.x & 31;
    const int ty = threadIdx.x >> 5; // 0..7
#pragma unroll
    for (int i = 0; i < 32; i += 8)
        t[ty + i][tx] = f2bf(in[(size_t)(by + ty + i) * N + bx + tx]);
    __syncthreads();
#pragma unroll
    for (int i = 0; i < 32; i += 8)
        out[(size_t)(bx + ty + i) * K + by + tx] = t[tx][ty + i];
}

// ---------------------------------------------------------------- MFMA GEMM (B^T, async staging)
// C[M,N] bf16 = A[M,K](bf16, row stride lda) @ W[K,N] + bias[N](fp32); WT[N][K] bf16.
// 128x128 tile, 4 waves, 4x4 16x16x32 MFMA, BK=32, global_load_lds width-16 (m97 structure).
#define BM 128
#define BN 128
#define BK 32

template <int ACT>
__global__ __launch_bounds__(256, 2) void gemm_bt_kernel(
    const u16* __restrict__ A, int lda, const u16* __restrict__ WT,
    const float* __restrict__ bias, u16* __restrict__ C,
    int M, int K, int N)
{
    __shared__ __align__(16) u16 Al[BM * BK];
    __shared__ __align__(16) u16 Wl[BN * BK];

    const int tid  = threadIdx.x;
    const int lane = tid & 63;
    const int w    = tid >> 6;
    const int wm = w >> 1, wn = w & 1;
    const int col = lane & 15, qq = lane >> 4;
    const size_t bm = (size_t)blockIdx.y * BM;
    const size_t bn = (size_t)blockIdx.x * BN;

    f32x4 acc[4][4];
#pragma unroll
    for (int mt = 0; mt < 4; mt++)
#pragma unroll
        for (int nt = 0; nt < 4; nt++) acc[mt][nt] = (f32x4){0.f, 0.f, 0.f, 0.f};

    // staging: flat 16B-chunk index f covers row=f>>2, sub=f&3 (4 chunks per 32-elem row)
    const int f0 = w * 128 + lane;
    const int f1 = f0 + 64;
    const u16* ga0 = A  + (bm + (f0 >> 2)) * (size_t)lda + (f0 & 3) * 8;
    const u16* ga1 = A  + (bm + (f1 >> 2)) * (size_t)lda + (f1 & 3) * 8;
    const u16* gw0 = WT + (bn + (f0 >> 2)) * (size_t)K   + (f0 & 3) * 8;
    const u16* gw1 = WT + (bn + (f1 >> 2)) * (size_t)K   + (f1 & 3) * 8;
    u16* la0 = &Al[(size_t)(w * 128) * 8];       // wave-uniform base; lanes scatter +lane*16B
    u16* la1 = &Al[(size_t)(w * 128 + 64) * 8];
    u16* lw0 = &Wl[(size_t)(w * 128) * 8];
    u16* lw1 = &Wl[(size_t)(w * 128 + 64) * 8];

    for (int k0 = 0; k0 < K; k0 += BK) {
        gld16(ga0 + k0, la0);
        gld16(ga1 + k0, la1);
        gld16(gw0 + k0, lw0);
        gld16(gw1 + k0, lw1);
        __syncthreads();

        bf16x8 af[4], bfr[4];
#pragma unroll
        for (int mt = 0; mt < 4; mt++)
            af[mt] = *(const bf16x8*)&Al[(wm * 64 + mt * 16 + col) * BK + qq * 8];
#pragma unroll
        for (int nt = 0; nt < 4; nt++)
            bfr[nt] = *(const bf16x8*)&Wl[(wn * 64 + nt * 16 + col) * BK + qq * 8];
#pragma unroll
        for (int mt = 0; mt < 4; mt++)
#pragma unroll
            for (int nt = 0; nt < 4; nt++)
                acc[mt][nt] = __builtin_amdgcn_mfma_f32_16x16x32_bf16(
                    af[mt], bfr[nt], acc[mt][nt], 0, 0, 0);
        __syncthreads();
    }

    float bv[4];
#pragma unroll
    for (int nt = 0; nt < 4; nt++)
        bv[nt] = bias[bn + wn * 64 + nt * 16 + col];

#pragma unroll
    for (int mt = 0; mt < 4; mt++) {
#pragma unroll
        for (int nt = 0; nt < 4; nt++) {
#pragma unroll
            for (int r = 0; r < 4; r++) {
                float v = acc[mt][nt][r] + bv[nt];
                if (ACT == 1) v = 0.5f * v * (1.0f + erff(v * 0.70710678118654752f));
                size_t rg = bm + wm * 64 + mt * 16 + qq * 4 + r;
                C[rg * (size_t)N + bn + wn * 64 + nt * 16 + col] = f2bf(v);
            }
        }
    }
}

// ---------------------------------------------------------------- flash attention (MFMA)
// grid (SEQ/BQ2, BATCH*HEADS); 256 thr = 4 waves; wave w owns q rows [16w,16w+16).
// Q fragments in registers; per 128-key tile: S=QK^T (scale folded post-MFMA), +bias,
// online softmax, P over K LDS region (wave-private rows -> no barrier), PV with Vt.
#define BQ2 64
#define BKV 128
#define LDQ 72    // K LDS row stride
#define LDP 136   // P/Vt LDS row stride

__global__ __launch_bounds__(256, 4) void fattn_kernel(
    const u16* __restrict__ Q, const u16* __restrict__ K,
    const u16* __restrict__ V, const float* __restrict__ ab,
    u16* __restrict__ O)
{
    __shared__ __align__(16) u16 KP[BKV * LDQ];   // 18,432 B (K stride 72; P stride 136, rows<64)
    __shared__ __align__(16) u16 Vt[HD * LDP];    // 17,408 B

    const int tid = threadIdx.x;
    const int lane = tid & 63;
    const int w = tid >> 6;
    const int col = lane & 15, qq = lane >> 4;
    const int qt = blockIdx.x;                    // 0..31
    const int b = blockIdx.y >> 4, h = blockIdx.y & 15;
    const size_t tok0 = (size_t)b * SEQ + (size_t)qt * BQ2;
    const int qrow0 = qt * BQ2;
    const int myrow = w * 16;

    // Q fragments: registers, loaded once (A-layout: m=col, k=qq*8+e within 32-chunk kk)
    bf16x8 aq[2];
#pragma unroll
    for (int kk = 0; kk < 2; kk++)
        aq[kk] = *(const bf16x8*)(Q + (tok0 + myrow + col) * EMB + h * HD + kk * 32 + qq * 8);

    float m_st[4], l_st[4];
    f32x4 o_acc[4];
#pragma unroll
    for (int r = 0; r < 4; r++) { m_st[r] = -1e30f; l_st[r] = 0.f; }
#pragma unroll
    for (int dt = 0; dt < 4; dt++) o_acc[dt] = (f32x4){0.f, 0.f, 0.f, 0.f};

    for (int kv0 = 0; kv0 < SEQ; kv0 += BKV) {
        // stage K tile [128][64] -> KP stride LDQ (vector 16B writes)
        for (int c = tid; c < BKV * 8; c += 256) {
            int kr = c >> 3, d0 = (c & 7) * 8;
            *(uint4*)&KP[kr * LDQ + d0] =
                *(const uint4*)(K + ((size_t)b * SEQ + kv0 + kr) * EMB + h * HD + d0);
        }
        // stage V transposed -> Vt[d][j], b64 writes (thread: 4 j x 8 d)
        {
            int jq = tid & 31, dg = tid >> 5;
            u16 v[4][8];
#pragma unroll
            for (int i = 0; i < 4; i++)
                *(uint4*)v[i] = *(const uint4*)(V + ((size_t)b * SEQ + kv0 + jq * 4 + i) * EMB
                                                + h * HD + dg * 8);
#pragma unroll
            for (int dd = 0; dd < 8; dd++) {
                ushort4 w4; w4.x = v[0][dd]; w4.y = v[1][dd]; w4.z = v[2][dd]; w4.w = v[3][dd];
                *(ushort4*)&Vt[(dg * 8 + dd) * LDP + jq * 4] = w4;
            }
        }
        __syncthreads();

        // S = Q K^T
        f32x4 s[8];
#pragma unroll
        for (int nt = 0; nt < 8; nt++) {
            bf16x8 bk0 = *(const bf16x8*)&KP[(nt * 16 + col) * LDQ + qq * 8];
            bf16x8 bk1 = *(const bf16x8*)&KP[(nt * 16 + col) * LDQ + 32 + qq * 8];
            f32x4 t = (f32x4){0.f, 0.f, 0.f, 0.f};
            t = __builtin_amdgcn_mfma_f32_16x16x32_bf16(aq[0], bk0, t, 0, 0, 0);
            t = __builtin_amdgcn_mfma_f32_16x16x32_bf16(aq[1], bk1, t, 0, 0, 0);
            s[nt] = t;
        }
        // scale (1/8) + bias
#pragma unroll
        for (int nt = 0; nt < 8; nt++)
#pragma unroll
            for (int r = 0; r < 4; r++)
                s[nt][r] = fmaf(s[nt][r], 0.125f,
                    ab[(size_t)(qrow0 + myrow + qq * 4 + r) * SEQ + kv0 + nt * 16 + col]);

        // online softmax (exp in place)
        float alpha[4];
#pragma unroll
        for (int r = 0; r < 4; r++) {
            float tm = s[0][r];
#pragma unroll
            for (int nt = 1; nt < 8; nt++) tm = fmaxf(tm, s[nt][r]);
#pragma unroll
            for (int msk = 1; msk < 16; msk <<= 1) tm = fmaxf(tm, __shfl_xor(tm, msk));
            float mnew = fmaxf(m_st[r], tm);
            alpha[r] = __expf(m_st[r] - mnew);
            m_st[r] = mnew;
            float rs = 0.f;
#pragma unroll
            for (int nt = 0; nt < 8; nt++) {
                float e = __expf(s[nt][r] - mnew);
                s[nt][r] = e;
                rs += e;
            }
#pragma unroll
            for (int msk = 1; msk < 16; msk <<= 1) rs += __shfl_xor(rs, msk);
            l_st[r] = l_st[r] * alpha[r] + rs;
        }
#pragma unroll
        for (int dt = 0; dt < 4; dt++)
#pragma unroll
            for (int r = 0; r < 4; r++) o_acc[dt][r] *= alpha[r];

        __syncthreads();   // all waves done reading K region

        // P write (bf16) over K region, stride LDP — wave-private rows, no barrier needed
#pragma unroll
        for (int nt = 0; nt < 8; nt++)
#pragma unroll
            for (int r = 0; r < 4; r++)
                KP[(myrow + qq * 4 + r) * LDP + nt * 16 + col] = f2bf(s[nt][r]);

        // O += P @ V
#pragma unroll
        for (int kk = 0; kk < 4; kk++) {
            bf16x8 ap = *(const bf16x8*)&KP[(myrow + col) * LDP + kk * 32 + qq * 8];
#pragma unroll
            for (int dt = 0; dt < 4; dt++) {
                bf16x8 bv = *(const bf16x8*)&Vt[(dt * 16 + col) * LDP + kk * 32 + qq * 8];
                o_acc[dt] = __builtin_amdgcn_mfma_f32_16x16x32_bf16(ap, bv, o_acc[dt], 0, 0, 0);
            }
        }
        __syncthreads();   // P/Vt reads done before next staging
    }

    // epilogue
#pragma unroll
    for (int r = 0; r < 4; r++) {
        float inv = 1.0f / l_st[r];
#pragma unroll
        for (int dt = 0; dt < 4; dt++)
            O[(tok0 + myrow + qq * 4 + r) * EMB + h * HD + dt * 16 + col]
                = f2bf(o_acc[dt][r] * inv);
    }
}

// ---------------------------------------------------------------- residual + LayerNorm
template <int AF32, int OUTF32>
__global__ __launch_bounds__(256) void ln_kernel(
    const void* __restrict__ A, const u16* __restrict__ R,
    const float* __restrict__ w, const float* __restrict__ bb,
    void* __restrict__ out)
{
    __shared__ float r1[4], r2[4];
    const int tid = threadIdx.x;
    const size_t row = blockIdx.x;

    float v[4];
    float s = 0.0f, s2 = 0.0f;
#pragma unroll
    for (int i = 0; i < 4; i++) {
        int c = tid + i * 256;
        float a = AF32 ? ((const float*)A)[row * EMB + c]
                       : bf2f(((const u16*)A)[row * EMB + c]);
        float t = a + bf2f(R[row * EMB + c]);
        v[i] = t;
        s += t; s2 += t * t;
    }
#pragma unroll
    for (int o = 32; o > 0; o >>= 1) {
        s  += __shfl_down(s, o);
        s2 += __shfl_down(s2, o);
    }
    if ((tid & 63) == 0) { r1[tid >> 6] = s; r2[tid >> 6] = s2; }
    __syncthreads();
    s  = r1[0] + r1[1] + r1[2] + r1[3];
    s2 = r2[0] + r2[1] + r2[2] + r2[3];

    float mu = s * (1.0f / EMB);
    float var = s2 * (1.0f / EMB) - mu * mu;
    float rs = rsqrtf(var + 1e-5f);

#pragma unroll
    for (int i = 0; i < 4; i++) {
        int c = tid + i * 256;
        float y = (v[i] - mu) * rs * w[c] + bb[c];
        if (OUTF32) ((float*)out)[row * EMB + c] = y;
        else        ((u16*)out)[row * EMB + c] = f2bf(y);
    }
}

// ---------------------------------------------------------------- launch
extern "C" void kernel_launch(void* const* d_in, const int* in_sizes, int n_in,
                              void* d_out, int out_size, void* d_ws, size_t ws_size,
                              hipStream_t stream)
{
    const float* x    = (const float*)d_in[0];
    const float* ab   = (const float*)d_in[1];
    const float* Wq   = (const float*)d_in[2];
    const float* bq   = (const float*)d_in[3];
    const float* WaK  = (const float*)d_in[4];
    const float* baK  = (const float*)d_in[5];
    const float* WbK  = (const float*)d_in[6];
    const float* bbK  = (const float*)d_in[7];
    const float* WaV  = (const float*)d_in[8];
    const float* baV  = (const float*)d_in[9];
    const float* WbV  = (const float*)d_in[10];
    const float* bbV  = (const float*)d_in[11];
    const float* Wo   = (const float*)d_in[12];
    const float* bo   = (const float*)d_in[13];
    const float* W1   = (const float*)d_in[14];
    const float* b1   = (const float*)d_in[15];
    const float* W2   = (const float*)d_in[16];
    const float* b2   = (const float*)d_in[17];
    const float* ln1w = (const float*)d_in[18];
    const float* ln1b = (const float*)d_in[19];
    const float* ln2w = (const float*)d_in[20];
    const float* ln2b = (const float*)d_in[21];

    u16* w = (u16*)d_ws;
    size_t o = 0;
    u16* WqT  = w + o; o += (size_t)EMB * EMB;     // 1Mi
    u16* WaKT = w + o; o += (size_t)EMB * LATD;    // 256Ki  (WaKT+WaVT contiguous = combined WT)
    u16* WaVT = w + o; o += (size_t)EMB * LATD;
    u16* WbKT = w + o; o += (size_t)LATD * EMB;
    u16* WbVT = w + o; o += (size_t)LATD * EMB;
    u16* WoT  = w + o; o += (size_t)EMB * EMB;
    u16* W1T  = w + o; o += (size_t)EMB * FFND;    // 4Mi
    u16* W2T  = w + o; o += (size_t)FFND * EMB;    // 4Mi
    u16* Qb   = w + o; o += (size_t)TOK * EMB;     // 4Mi
    u16* Kb   = w + o; o += (size_t)TOK * EMB;
    u16* Vb   = w + o; o += (size_t)TOK * EMB;
    u16* aOb  = w + o; o += (size_t)TOK * EMB;
    u16* projb= w + o; o += (size_t)TOK * EMB;
    u16* hb   = w + o; o += (size_t)TOK * EMB;
    float* bKV = (float*)(w + o); o += 1024;       // 512 fp32 concat bias
    // reuse (non-overlapping lifetimes):
    u16* xb  = projb;                         // bf16 x; dead before proj written (ln1 reads fp32 x)
    u16* KVa = aOb;                           // [TOK][512] Ka|Va; dead before fattn writes aOb
    u16* f1  = Qb;                            // spans Qb..aOb = TOK*FFND
    u16* f2  = projb;                         // xb/proj dead after ln1

    dim3 blk(256);

    // x -> bf16
    cvt_f32_bf16_kernel<<<dim3(2048), blk, 0, stream>>>(x, xb, TOK * EMB / 8);
    concat_bias_kernel<<<dim3(2), blk, 0, stream>>>(baK, baV, bKV);

    // weight transposes + fp32->bf16 convert
    transpose_cvt_kernel<<<dim3(EMB / 32, EMB / 32), blk, 0, stream>>>(Wq, WqT, EMB, EMB);
    transpose_cvt_kernel<<<dim3(LATD / 32, EMB / 32), blk, 0, stream>>>(WaK, WaKT, EMB, LATD);
    transpose_cvt_kernel<<<dim3(LATD / 32, EMB / 32), blk, 0, stream>>>(WaV, WaVT, EMB, LATD);
    transpose_cvt_kernel<<<dim3(EMB / 32, LATD / 32), blk, 0, stream>>>(WbK, WbKT, LATD, EMB);
    transpose_cvt_kernel<<<dim3(EMB / 32, LATD / 32), blk, 0, stream>>>(WbV, WbVT, LATD, EMB);
    transpose_cvt_kernel<<<dim3(EMB / 32, EMB / 32), blk, 0, stream>>>(Wo, WoT, EMB, EMB);
    transpose_cvt_kernel<<<dim3(FFND / 32, EMB / 32), blk, 0, stream>>>(W1, W1T, EMB, FFND);
    transpose_cvt_kernel<<<dim3(EMB / 32, FFND / 32), blk, 0, stream>>>(W2, W2T, FFND, EMB);

    // Q = x @ Wq + bq
    gemm_bt_kernel<0><<<dim3(EMB / BN, TOK / BM), blk, 0, stream>>>(xb, EMB, WqT, bq, Qb, TOK, EMB, EMB);
    // [Ka|Va] = x @ [WaK|WaV] + [baK|baV]   (N=512 fused)
    gemm_bt_kernel<0><<<dim3(512 / BN, TOK / BM), blk, 0, stream>>>(xb, EMB, WaKT, bKV, KVa, TOK, EMB, 512);
    // K = Ka @ WbK + bbK ; V = Va @ WbV + bbV   (A row stride 512)
    gemm_bt_kernel<0><<<dim3(EMB / BN, TOK / BM), blk, 0, stream>>>(KVa, 512, WbKT, bbK, Kb, TOK, LATD, EMB);
    gemm_bt_kernel<0><<<dim3(EMB / BN, TOK / BM), blk, 0, stream>>>(KVa + LATD, 512, WbVT, bbV, Vb, TOK, LATD, EMB);

    // flash attention -> aOb
    fattn_kernel<<<dim3(SEQ / BQ2, BATCH * HEADS), blk, 0, stream>>>(Qb, Kb, Vb, ab, aOb);

    // proj = aO @ Wo + bo
    gemm_bt_kernel<0><<<dim3(EMB / BN, TOK / BM), blk, 0, stream>>>(aOb, EMB, WoT, bo, projb, TOK, EMB, EMB);

    // h = LN(x + proj) -> bf16 hb
    ln_kernel<1,0><<<dim3(TOK), blk, 0, stream>>>(x, projb, ln1w, ln1b, hb);

    // f1 = gelu(h @ W1 + b1) ; f2 = f1 @ W2 + b2
    gemm_bt_kernel<1><<<dim3(FFND / BN, TOK / BM), blk, 0, stream>>>(hb, EMB, W1T, b1, f1, TOK, EMB, FFND);
    gemm_bt_kernel<0><<<dim3(EMB / BN, TOK / BM), blk, 0, stream>>>(f1, FFND, W2T, b2, f2, TOK, FFND, EMB);

    // out = LN(h + f2) -> fp32 d_out
    ln_kernel<0,1><<<dim3(TOK), blk, 0, stream>>>(hb, f2, ln2w, ln2b, (float*)d_out);
}

// Round 6
// 496.958 us; speedup vs baseline: 11.5630x; 1.0559x over previous
//
#include <hip/hip_runtime.h>
#include <hip/hip_bf16.h>
#include <math.h>

typedef unsigned short u16;
typedef short bf16x8 __attribute__((ext_vector_type(8)));
typedef float f32x4 __attribute__((ext_vector_type(4)));

#define EMB   1024
#define HEADS 16
#define HD    64
#define LATD  256
#define FFND  4096
#define BATCH 2
#define SEQ   2048
#define TOK   (BATCH*SEQ)   // 4096

__device__ __forceinline__ float bf2f(u16 u) {
    union { unsigned int i; float f; } x; x.i = ((unsigned int)u) << 16; return x.f;
}
__device__ __forceinline__ u16 f2bf(float f) {
    union { float f; unsigned int i; } x; x.f = f;
    unsigned int i = x.i;
    unsigned int lsb = (i >> 16) & 1u;
    i += 0x7fffu + lsb;       // round-to-nearest-even
    return (u16)(i >> 16);
}
__device__ __forceinline__ void gld16(const u16* g, u16* l) {
    __builtin_amdgcn_global_load_lds(
        (const __attribute__((address_space(1))) void*)g,
        (__attribute__((address_space(3))) void*)l, 16, 0, 0);
}

// ---------------------------------------------------------------- fp32 -> bf16 convert
__global__ __launch_bounds__(256) void cvt_f32_bf16_kernel(
    const float* __restrict__ in, u16* __restrict__ out, int n8)
{
    int i = blockIdx.x * 256 + threadIdx.x;
    int stride = gridDim.x * 256;
    for (; i < n8; i += stride) {
        float4 f0 = *(const float4*)(in + (size_t)i * 8);
        float4 f1 = *(const float4*)(in + (size_t)i * 8 + 4);
        u16 e[8];
        e[0] = f2bf(f0.x); e[1] = f2bf(f0.y); e[2] = f2bf(f0.z); e[3] = f2bf(f0.w);
        e[4] = f2bf(f1.x); e[5] = f2bf(f1.y); e[6] = f2bf(f1.z); e[7] = f2bf(f1.w);
        *(uint4*)(out + (size_t)i * 8) = *(const uint4*)e;
    }
}

// ---------------------------------------------------------------- concat 2 bias vectors (256 each)
__global__ __launch_bounds__(256) void concat_bias_kernel(
    const float* __restrict__ a, const float* __restrict__ b, float* __restrict__ out)
{
    int i = blockIdx.x * 256 + threadIdx.x;   // 0..511
    out[i] = (i < 256) ? a[i] : b[i - 256];
}

// ---------------------------------------------------------------- permute attn_bias into MFMA C-frag order
// abP[qt][kt][w][mt][nt][lane][r], fp32. grid (16 kt, 16 qt), 256 thr.
__global__ __launch_bounds__(256) void permute_ab_kernel(
    const float* __restrict__ ab, float* __restrict__ abP)
{
    const int kt = blockIdx.x, qt = blockIdx.y;
    const int tid = threadIdx.x;
    const int w = tid >> 6, lane = tid & 63, qq = (lane >> 4), col = lane & 15;
    float* out = abP + ((size_t)qt * 16 + kt) * 16384 + (size_t)w * 4096;
#pragma unroll
    for (int mt = 0; mt < 2; mt++)
#pragma unroll
        for (int nt = 0; nt < 8; nt++) {
            float4 v;
            const float* src = ab + (size_t)(qt * 128 + w * 32 + mt * 16 + qq * 4) * SEQ
                               + kt * 128 + nt * 16 + col;
            v.x = src[0]; v.y = src[SEQ]; v.z = src[2 * SEQ]; v.w = src[3 * SEQ];
            *(float4*)(out + ((mt * 8 + nt) * 256) + lane * 4) = v;
        }
}

// ---------------------------------------------------------------- transpose + fp32->bf16 convert
__global__ __launch_bounds__(256) void transpose_cvt_kernel(
    const float* __restrict__ in, u16* __restrict__ out, int K, int N)
{
    __shared__ u16 t[32][33];
    const int bx = blockIdx.x * 32;  // n base
    const int by = blockIdx.y * 32;  // k base
    const int tx = threadIdx.x & 31;
    const int ty = threadIdx.x >> 5; // 0..7
#pragma unroll
    for (int i = 0; i < 32; i += 8)
        t[ty + i][tx] = f2bf(in[(size_t)(by + ty + i) * N + bx + tx]);
    __syncthreads();
#pragma unroll
    for (int i = 0; i < 32; i += 8)
        out[(size_t)(bx + ty + i) * K + by + tx] = t[tx][ty + i];
}

// ---------------------------------------------------------------- MFMA GEMM (B^T, async staging)
// C[M,N] bf16 = A[M,K](bf16, lda) @ W[K,N] + bias[N](fp32); WT[N][K] bf16.
// BM=128, BNv in {128,64}. 4 waves; wave covers 64m x (BNv/2)n, 4 x NT 16x16x32 MFMA, BK=32.
#define BM 128
#define BK 32

template <int ACT, int BNv>
__global__ __launch_bounds__(256, 2) void gemm_bt_kernel(
    const u16* __restrict__ A, int lda, const u16* __restrict__ WT,
    const float* __restrict__ bias, u16* __restrict__ C,
    int M, int K, int N)
{
    const int NT = BNv / 32;      // n-tiles per wave
    const int WN = BNv / 2;       // n span per wave
    __shared__ __align__(16) u16 Al[BM * BK];
    __shared__ __align__(16) u16 Wl[BNv * BK];

    const int tid  = threadIdx.x;
    const int lane = tid & 63;
    const int w    = tid >> 6;
    const int wm = w >> 1, wn = w & 1;
    const int col = lane & 15, qq = lane >> 4;
    const size_t bm = (size_t)blockIdx.y * BM;
    const size_t bn = (size_t)blockIdx.x * BNv;

    f32x4 acc[4][NT];
#pragma unroll
    for (int mt = 0; mt < 4; mt++)
#pragma unroll
        for (int nt = 0; nt < NT; nt++) acc[mt][nt] = (f32x4){0.f, 0.f, 0.f, 0.f};

    // A: 512 chunks of 16B; wave owns 128 (2/lane). W: BNv*4 chunks; wave owns BNv (BNv/64 per lane).
    const int fa0 = w * 128 + lane, fa1 = fa0 + 64;
    const u16* ga0 = A + (bm + (fa0 >> 2)) * (size_t)lda + (fa0 & 3) * 8;
    const u16* ga1 = A + (bm + (fa1 >> 2)) * (size_t)lda + (fa1 & 3) * 8;
    u16* la0 = &Al[(size_t)(w * 128) * 8];
    u16* la1 = &Al[(size_t)(w * 128 + 64) * 8];

    const int fw0 = w * BNv + lane;
    const u16* gw0 = WT + (bn + (fw0 >> 2)) * (size_t)K + (fw0 & 3) * 8;
    u16* lw0 = &Wl[(size_t)(w * BNv) * 8];
    const int fw1 = w * BNv + 64 + lane;   // only used when BNv==128
    const u16* gw1 = WT + (bn + (fw1 >> 2)) * (size_t)K + (fw1 & 3) * 8;
    u16* lw1 = &Wl[(size_t)(w * BNv + 64) * 8];

    for (int k0 = 0; k0 < K; k0 += BK) {
        gld16(ga0 + k0, la0);
        gld16(ga1 + k0, la1);
        gld16(gw0 + k0, lw0);
        if (BNv == 128) gld16(gw1 + k0, lw1);
        __syncthreads();

        bf16x8 af[4], bfr[NT];
#pragma unroll
        for (int mt = 0; mt < 4; mt++)
            af[mt] = *(const bf16x8*)&Al[(wm * 64 + mt * 16 + col) * BK + qq * 8];
#pragma unroll
        for (int nt = 0; nt < NT; nt++)
            bfr[nt] = *(const bf16x8*)&Wl[(wn * WN + nt * 16 + col) * BK + qq * 8];
#pragma unroll
        for (int mt = 0; mt < 4; mt++)
#pragma unroll
            for (int nt = 0; nt < NT; nt++)
                acc[mt][nt] = __builtin_amdgcn_mfma_f32_16x16x32_bf16(
                    af[mt], bfr[nt], acc[mt][nt], 0, 0, 0);
        __syncthreads();
    }

    float bv[NT];
#pragma unroll
    for (int nt = 0; nt < NT; nt++)
        bv[nt] = bias[bn + wn * WN + nt * 16 + col];

#pragma unroll
    for (int mt = 0; mt < 4; mt++) {
#pragma unroll
        for (int nt = 0; nt < NT; nt++) {
#pragma unroll
            for (int r = 0; r < 4; r++) {
                float v = acc[mt][nt][r] + bv[nt];
                if (ACT == 1) v = 0.5f * v * (1.0f + erff(v * 0.70710678118654752f));
                size_t rg = bm + wm * 64 + mt * 16 + qq * 4 + r;
                C[rg * (size_t)N + bn + wn * WN + nt * 16 + col] = f2bf(v);
            }
        }
    }
}

// ---------------------------------------------------------------- flash attention (MFMA)
// grid (SEQ/BQ, BATCH*HEADS); 256 thr = 4 waves; wave w owns q rows [32w, 32w+32) (2 m-tiles).
// Q in regs; per 128-key tile: reg-prefetch next K/V, S=QK^T, +permuted bias, online softmax,
// P -> separate LDS buffer (wave-private rows, no extra barrier), PV with Vt. 2 barriers/tile.
#define BQ  128
#define BKV 128
#define LDK 72
#define LDP 136

__global__ __launch_bounds__(256, 2) void fattn_kernel(
    const u16* __restrict__ Q, const u16* __restrict__ K,
    const u16* __restrict__ V, const float* __restrict__ abP,
    u16* __restrict__ O)
{
    __shared__ __align__(16) u16 Ks[BKV * LDK];   // 18,432 B
    __shared__ __align__(16) u16 Ps[BQ * LDP];    // 34,816 B
    __shared__ __align__(16) u16 Vt[HD * LDP];    // 17,408 B  (total 70,656)

    const int tid = threadIdx.x;
    const int lane = tid & 63;
    const int w = tid >> 6;
    const int col = lane & 15, qq = lane >> 4;
    const int qt = blockIdx.x;                    // 0..15
    const int b = blockIdx.y >> 4, h = blockIdx.y & 15;
    const size_t tok0 = (size_t)b * SEQ + (size_t)qt * BQ;
    const int wrow = w * 32;
    const size_t kvbase = (size_t)b * SEQ * EMB + h * HD;
    const int jq = tid & 31, dg = tid >> 5;

    // Q fragments in registers (A-layout)
    bf16x8 aq[2][2];
#pragma unroll
    for (int mt = 0; mt < 2; mt++)
#pragma unroll
        for (int kk = 0; kk < 2; kk++)
            aq[mt][kk] = *(const bf16x8*)(Q + (tok0 + wrow + mt * 16 + col) * EMB
                                          + h * HD + kk * 32 + qq * 8);

    float m_st[2][4], l_st[2][4];
    f32x4 o_acc[2][4];
#pragma unroll
    for (int mt = 0; mt < 2; mt++)
#pragma unroll
        for (int r = 0; r < 4; r++) { m_st[mt][r] = -1e30f; l_st[mt][r] = 0.f; }
#pragma unroll
    for (int mt = 0; mt < 2; mt++)
#pragma unroll
        for (int dt = 0; dt < 4; dt++) o_acc[mt][dt] = (f32x4){0.f, 0.f, 0.f, 0.f};

    uint4 kreg[4], vreg[4];
#define LOADKV(KV0) do {                                                             \
        _Pragma("unroll")                                                            \
        for (int i = 0; i < 4; i++) {                                                \
            int c = tid + i * 256;                                                   \
            kreg[i] = *(const uint4*)(K + kvbase + (size_t)((KV0) + (c >> 3)) * EMB  \
                                      + (c & 7) * 8);                                \
        }                                                                            \
        _Pragma("unroll")                                                            \
        for (int i = 0; i < 4; i++)                                                  \
            vreg[i] = *(const uint4*)(V + kvbase + (size_t)((KV0) + jq * 4 + i) * EMB\
                                      + dg * 8);                                     \
    } while (0)

    LOADKV(0);

    for (int t = 0; t < SEQ / BKV; t++) {
        // staged regs -> LDS
#pragma unroll
        for (int i = 0; i < 4; i++) {
            int c = tid + i * 256;
            *(uint4*)&Ks[(c >> 3) * LDK + (c & 7) * 8] = kreg[i];
        }
        {
            u16 vv[4][8];
#pragma unroll
            for (int i = 0; i < 4; i++) *(uint4*)vv[i] = vreg[i];
#pragma unroll
            for (int dd = 0; dd < 8; dd++) {
                ushort4 w4; w4.x = vv[0][dd]; w4.y = vv[1][dd]; w4.z = vv[2][dd]; w4.w = vv[3][dd];
                *(ushort4*)&Vt[(dg * 8 + dd) * LDP + jq * 4] = w4;
            }
        }
        __syncthreads();

        // prefetch next tile's K/V while computing this one
        if (t + 1 < SEQ / BKV) LOADKV((t + 1) * BKV);

        // bias fragments: 16 coalesced float4 loads
        const float* abb = abP + (((size_t)qt * 16 + t) * 4 + w) * 4096;
        float4 abv[2][8];
#pragma unroll
        for (int mt = 0; mt < 2; mt++)
#pragma unroll
            for (int nt = 0; nt < 8; nt++)
                abv[mt][nt] = *(const float4*)(abb + (mt * 8 + nt) * 256 + lane * 4);

        // S = Q K^T
        f32x4 s[2][8];
#pragma unroll
        for (int nt = 0; nt < 8; nt++) {
            bf16x8 bk0 = *(const bf16x8*)&Ks[(nt * 16 + col) * LDK + qq * 8];
            bf16x8 bk1 = *(const bf16x8*)&Ks[(nt * 16 + col) * LDK + 32 + qq * 8];
#pragma unroll
            for (int mt = 0; mt < 2; mt++) {
                f32x4 acc0 = (f32x4){0.f, 0.f, 0.f, 0.f};
                acc0 = __builtin_amdgcn_mfma_f32_16x16x32_bf16(aq[mt][0], bk0, acc0, 0, 0, 0);
                acc0 = __builtin_amdgcn_mfma_f32_16x16x32_bf16(aq[mt][1], bk1, acc0, 0, 0, 0);
                s[mt][nt] = acc0;
            }
        }
        // scale + bias
#pragma unroll
        for (int mt = 0; mt < 2; mt++)
#pragma unroll
            for (int nt = 0; nt < 8; nt++) {
                s[mt][nt][0] = fmaf(s[mt][nt][0], 0.125f, abv[mt][nt].x);
                s[mt][nt][1] = fmaf(s[mt][nt][1], 0.125f, abv[mt][nt].y);
                s[mt][nt][2] = fmaf(s[mt][nt][2], 0.125f, abv[mt][nt].z);
                s[mt][nt][3] = fmaf(s[mt][nt][3], 0.125f, abv[mt][nt].w);
            }

        // online softmax (exp in place)
        float alpha[2][4];
#pragma unroll
        for (int mt = 0; mt < 2; mt++)
#pragma unroll
            for (int r = 0; r < 4; r++) {
                float tm = s[mt][0][r];
#pragma unroll
                for (int nt = 1; nt < 8; nt++) tm = fmaxf(tm, s[mt][nt][r]);
#pragma unroll
                for (int msk = 1; msk < 16; msk <<= 1) tm = fmaxf(tm, __shfl_xor(tm, msk));
                float mnew = fmaxf(m_st[mt][r], tm);
                alpha[mt][r] = __expf(m_st[mt][r] - mnew);
                m_st[mt][r] = mnew;
                float rs = 0.f;
#pragma unroll
                for (int nt = 0; nt < 8; nt++) {
                    float e = __expf(s[mt][nt][r] - mnew);
                    s[mt][nt][r] = e;
                    rs += e;
                }
#pragma unroll
                for (int msk = 1; msk < 16; msk <<= 1) rs += __shfl_xor(rs, msk);
                l_st[mt][r] = l_st[mt][r] * alpha[mt][r] + rs;
            }
#pragma unroll
        for (int mt = 0; mt < 2; mt++)
#pragma unroll
            for (int dt = 0; dt < 4; dt++)
#pragma unroll
                for (int r = 0; r < 4; r++) o_acc[mt][dt][r] *= alpha[mt][r];

        // P write (wave-private rows; same-wave LDS RAW is in-order, no barrier)
#pragma unroll
        for (int mt = 0; mt < 2; mt++)
#pragma unroll
            for (int nt = 0; nt < 8; nt++)
#pragma unroll
                for (int r = 0; r < 4; r++)
                    Ps[(wrow + mt * 16 + qq * 4 + r) * LDP + nt * 16 + col] = f2bf(s[mt][nt][r]);

        // O += P @ V
#pragma unroll
        for (int kk = 0; kk < 4; kk++) {
            bf16x8 ap0 = *(const bf16x8*)&Ps[(wrow + col) * LDP + kk * 32 + qq * 8];
            bf16x8 ap1 = *(const bf16x8*)&Ps[(wrow + 16 + col) * LDP + kk * 32 + qq * 8];
#pragma unroll
            for (int dt = 0; dt < 4; dt++) {
                bf16x8 bv = *(const bf16x8*)&Vt[(dt * 16 + col) * LDP + kk * 32 + qq * 8];
                o_acc[0][dt] = __builtin_amdgcn_mfma_f32_16x16x32_bf16(ap0, bv, o_acc[0][dt], 0, 0, 0);
                o_acc[1][dt] = __builtin_amdgcn_mfma_f32_16x16x32_bf16(ap1, bv, o_acc[1][dt], 0, 0, 0);
            }
        }
        __syncthreads();   // Ks/Vt reads done before next staging overwrite
    }
#undef LOADKV

    // epilogue
#pragma unroll
    for (int mt = 0; mt < 2; mt++)
#pragma unroll
        for (int r = 0; r < 4; r++) {
            float inv = 1.0f / l_st[mt][r];
#pragma unroll
            for (int dt = 0; dt < 4; dt++)
                O[(tok0 + wrow + mt * 16 + qq * 4 + r) * EMB + h * HD + dt * 16 + col]
                    = f2bf(o_acc[mt][dt][r] * inv);
        }
}

// ---------------------------------------------------------------- residual + LayerNorm
template <int AF32, int OUTF32>
__global__ __launch_bounds__(256) void ln_kernel(
    const void* __restrict__ A, const u16* __restrict__ R,
    const float* __restrict__ w, const float* __restrict__ bb,
    void* __restrict__ out)
{
    __shared__ float r1[4], r2[4];
    const int tid = threadIdx.x;
    const size_t row = blockIdx.x;

    float v[4];
    float s = 0.0f, s2 = 0.0f;
#pragma unroll
    for (int i = 0; i < 4; i++) {
        int c = tid + i * 256;
        float a = AF32 ? ((const float*)A)[row * EMB + c]
                       : bf2f(((const u16*)A)[row * EMB + c]);
        float t = a + bf2f(R[row * EMB + c]);
        v[i] = t;
        s += t; s2 += t * t;
    }
#pragma unroll
    for (int o = 32; o > 0; o >>= 1) {
        s  += __shfl_down(s, o);
        s2 += __shfl_down(s2, o);
    }
    if ((tid & 63) == 0) { r1[tid >> 6] = s; r2[tid >> 6] = s2; }
    __syncthreads();
    s  = r1[0] + r1[1] + r1[2] + r1[3];
    s2 = r2[0] + r2[1] + r2[2] + r2[3];

    float mu = s * (1.0f / EMB);
    float var = s2 * (1.0f / EMB) - mu * mu;
    float rs = rsqrtf(var + 1e-5f);

#pragma unroll
    for (int i = 0; i < 4; i++) {
        int c = tid + i * 256;
        float y = (v[i] - mu) * rs * w[c] + bb[c];
        if (OUTF32) ((float*)out)[row * EMB + c] = y;
        else        ((u16*)out)[row * EMB + c] = f2bf(y);
    }
}

// ---------------------------------------------------------------- launch
extern "C" void kernel_launch(void* const* d_in, const int* in_sizes, int n_in,
                              void* d_out, int out_size, void* d_ws, size_t ws_size,
                              hipStream_t stream)
{
    const float* x    = (const float*)d_in[0];
    const float* ab   = (const float*)d_in[1];
    const float* Wq   = (const float*)d_in[2];
    const float* bq   = (const float*)d_in[3];
    const float* WaK  = (const float*)d_in[4];
    const float* baK  = (const float*)d_in[5];
    const float* WbK  = (const float*)d_in[6];
    const float* bbK  = (const float*)d_in[7];
    const float* WaV  = (const float*)d_in[8];
    const float* baV  = (const float*)d_in[9];
    const float* WbV  = (const float*)d_in[10];
    const float* bbV  = (const float*)d_in[11];
    const float* Wo   = (const float*)d_in[12];
    const float* bo   = (const float*)d_in[13];
    const float* W1   = (const float*)d_in[14];
    const float* b1   = (const float*)d_in[15];
    const float* W2   = (const float*)d_in[16];
    const float* b2   = (const float*)d_in[17];
    const float* ln1w = (const float*)d_in[18];
    const float* ln1b = (const float*)d_in[19];
    const float* ln2w = (const float*)d_in[20];
    const float* ln2b = (const float*)d_in[21];

    u16* w = (u16*)d_ws;
    size_t o = 0;
    u16* WqT  = w + o; o += (size_t)EMB * EMB;
    u16* WaKT = w + o; o += (size_t)EMB * LATD;    // WaKT+WaVT contiguous = combined WT
    u16* WaVT = w + o; o += (size_t)EMB * LATD;
    u16* WbKT = w + o; o += (size_t)LATD * EMB;
    u16* WbVT = w + o; o += (size_t)LATD * EMB;
    u16* WoT  = w + o; o += (size_t)EMB * EMB;
    u16* W1T  = w + o; o += (size_t)EMB * FFND;
    u16* W2T  = w + o; o += (size_t)FFND * EMB;
    u16* Qb   = w + o; o += (size_t)TOK * EMB;
    u16* Kb   = w + o; o += (size_t)TOK * EMB;
    u16* Vb   = w + o; o += (size_t)TOK * EMB;
    u16* aOb  = w + o; o += (size_t)TOK * EMB;
    u16* projb= w + o; o += (size_t)TOK * EMB;
    u16* hb   = w + o; o += (size_t)TOK * EMB;
    u16* xb   = w + o; o += (size_t)TOK * EMB;     // bf16 x (own slot)
    float* bKV = (float*)(w + o); o += 1024;       // 512 fp32 concat bias
    // overlays (non-overlapping lifetimes):
    float* abP = (float*)projb;               // 16.8 MB = projb+hb exactly; dead after fattn
    u16* KVa = aOb;                           // [TOK][512]; dead before fattn writes aOb
    u16* f1  = Qb;                            // spans Qb..aOb = TOK*FFND
    u16* f2  = projb;                         // abP/proj dead after ln1

    dim3 blk(256);

    cvt_f32_bf16_kernel<<<dim3(2048), blk, 0, stream>>>(x, xb, TOK * EMB / 8);
    concat_bias_kernel<<<dim3(2), blk, 0, stream>>>(baK, baV, bKV);
    permute_ab_kernel<<<dim3(16, 16), blk, 0, stream>>>(ab, abP);

    transpose_cvt_kernel<<<dim3(EMB / 32, EMB / 32), blk, 0, stream>>>(Wq, WqT, EMB, EMB);
    transpose_cvt_kernel<<<dim3(LATD / 32, EMB / 32), blk, 0, stream>>>(WaK, WaKT, EMB, LATD);
    transpose_cvt_kernel<<<dim3(LATD / 32, EMB / 32), blk, 0, stream>>>(WaV, WaVT, EMB, LATD);
    transpose_cvt_kernel<<<dim3(EMB / 32, LATD / 32), blk, 0, stream>>>(WbK, WbKT, LATD, EMB);
    transpose_cvt_kernel<<<dim3(EMB / 32, LATD / 32), blk, 0, stream>>>(WbV, WbVT, LATD, EMB);
    transpose_cvt_kernel<<<dim3(EMB / 32, EMB / 32), blk, 0, stream>>>(Wo, WoT, EMB, EMB);
    transpose_cvt_kernel<<<dim3(FFND / 32, EMB / 32), blk, 0, stream>>>(W1, W1T, EMB, FFND);
    transpose_cvt_kernel<<<dim3(EMB / 32, FFND / 32), blk, 0, stream>>>(W2, W2T, FFND, EMB);

    // Q = x @ Wq + bq                                  (512 blocks)
    gemm_bt_kernel<0,64><<<dim3(EMB / 64, TOK / BM), blk, 0, stream>>>(xb, EMB, WqT, bq, Qb, TOK, EMB, EMB);
    // [Ka|Va] = x @ [WaK|WaV] + [baK|baV]              (256 blocks)
    gemm_bt_kernel<0,64><<<dim3(512 / 64, TOK / BM), blk, 0, stream>>>(xb, EMB, WaKT, bKV, KVa, TOK, EMB, 512);
    // K = Ka @ WbK + bbK ; V = Va @ WbV + bbV          (512 blocks each)
    gemm_bt_kernel<0,64><<<dim3(EMB / 64, TOK / BM), blk, 0, stream>>>(KVa, 512, WbKT, bbK, Kb, TOK, LATD, EMB);
    gemm_bt_kernel<0,64><<<dim3(EMB / 64, TOK / BM), blk, 0, stream>>>(KVa + LATD, 512, WbVT, bbV, Vb, TOK, LATD, EMB);

    // flash attention -> aOb                           (512 blocks)
    fattn_kernel<<<dim3(SEQ / BQ, BATCH * HEADS), blk, 0, stream>>>(Qb, Kb, Vb, abP, aOb);

    // proj = aO @ Wo + bo                              (512 blocks)
    gemm_bt_kernel<0,64><<<dim3(EMB / 64, TOK / BM), blk, 0, stream>>>(aOb, EMB, WoT, bo, projb, TOK, EMB, EMB);

    // h = LN(x + proj) -> bf16 hb
    ln_kernel<1,0><<<dim3(TOK), blk, 0, stream>>>(x, projb, ln1w, ln1b, hb);

    // f1 = gelu(h @ W1 + b1)                           (1024 blocks)
    gemm_bt_kernel<1,128><<<dim3(FFND / 128, TOK / BM), blk, 0, stream>>>(hb, EMB, W1T, b1, f1, TOK, EMB, FFND);
    // f2 = f1 @ W2 + b2                                (512 blocks)
    gemm_bt_kernel<0,64><<<dim3(EMB / 64, TOK / BM), blk, 0, stream>>>(f1, FFND, W2T, b2, f2, TOK, FFND, EMB);

    // out = LN(h + f2) -> fp32 d_out
    ln_kernel<0,1><<<dim3(TOK), blk, 0, stream>>>(hb, f2, ln2w, ln2b, (float*)d_out);
}

// Round 8
// 457.053 us; speedup vs baseline: 12.5726x; 1.0873x over previous
//
#include <hip/hip_runtime.h>
#include <hip/hip_bf16.h>
#include <math.h>

typedef unsigned short u16;
typedef short bf16x8 __attribute__((ext_vector_type(8)));
typedef float f32x4 __attribute__((ext_vector_type(4)));

#define EMB   1024
#define HEADS 16
#define HD    64
#define LATD  256
#define FFND  4096
#define BATCH 2
#define SEQ   2048
#define TOK   (BATCH*SEQ)   // 4096

__device__ __forceinline__ float bf2f(u16 u) {
    union { unsigned int i; float f; } x; x.i = ((unsigned int)u) << 16; return x.f;
}
__device__ __forceinline__ u16 f2bf(float f) {
    union { float f; unsigned int i; } x; x.f = f;
    unsigned int i = x.i;
    unsigned int lsb = (i >> 16) & 1u;
    i += 0x7fffu + lsb;       // round-to-nearest-even
    return (u16)(i >> 16);
}
__device__ __forceinline__ void gld16(const u16* g, u16* l) {
    __builtin_amdgcn_global_load_lds(
        (const __attribute__((address_space(1))) void*)g,
        (__attribute__((address_space(3))) void*)l, 16, 0, 0);
}

// ---------------------------------------------------------------- fp32 -> bf16 convert
__global__ __launch_bounds__(256) void cvt_f32_bf16_kernel(
    const float* __restrict__ in, u16* __restrict__ out, int n8)
{
    int i = blockIdx.x * 256 + threadIdx.x;
    int stride = gridDim.x * 256;
    for (; i < n8; i += stride) {
        float4 f0 = *(const float4*)(in + (size_t)i * 8);
        float4 f1 = *(const float4*)(in + (size_t)i * 8 + 4);
        u16 e[8];
        e[0] = f2bf(f0.x); e[1] = f2bf(f0.y); e[2] = f2bf(f0.z); e[3] = f2bf(f0.w);
        e[4] = f2bf(f1.x); e[5] = f2bf(f1.y); e[6] = f2bf(f1.z); e[7] = f2bf(f1.w);
        *(uint4*)(out + (size_t)i * 8) = *(const uint4*)e;
    }
}

// ---------------------------------------------------------------- concat 2 bias vectors (256 each)
__global__ __launch_bounds__(256) void concat_bias_kernel(
    const float* __restrict__ a, const float* __restrict__ b, float* __restrict__ out)
{
    int i = blockIdx.x * 256 + threadIdx.x;   // 0..511
    out[i] = (i < 256) ? a[i] : b[i - 256];
}

// ---------------------------------------------------------------- permute attn_bias into MFMA C-frag order
// abP[qt][kt][w][mt][nt][lane][r], fp32. grid (16 kt, 16 qt), 256 thr.
__global__ __launch_bounds__(256) void permute_ab_kernel(
    const float* __restrict__ ab, float* __restrict__ abP)
{
    const int kt = blockIdx.x, qt = blockIdx.y;
    const int tid = threadIdx.x;
    const int w = tid >> 6, lane = tid & 63, qq = (lane >> 4), col = lane & 15;
    float* out = abP + ((size_t)qt * 16 + kt) * 16384 + (size_t)w * 4096;
#pragma unroll
    for (int mt = 0; mt < 2; mt++)
#pragma unroll
        for (int nt = 0; nt < 8; nt++) {
            float4 v;
            const float* src = ab + (size_t)(qt * 128 + w * 32 + mt * 16 + qq * 4) * SEQ
                               + kt * 128 + nt * 16 + col;
            v.x = src[0]; v.y = src[SEQ]; v.z = src[2 * SEQ]; v.w = src[3 * SEQ];
            *(float4*)(out + ((mt * 8 + nt) * 256) + lane * 4) = v;
        }
}

// ---------------------------------------------------------------- merged transpose+cvt (8 matrices)
struct TDesc { const float* src; u16* dst; int K; int N; int ofs; };
struct TTable { TDesc d[8]; };

__global__ __launch_bounds__(256) void transpose_all_kernel(TTable tt)
{
    __shared__ u16 t[32][33];
    int tb = blockIdx.x, e = 0;
#pragma unroll
    for (int i = 1; i < 8; i++) if (tb >= tt.d[i].ofs) e = i;
    const float* src = tt.d[e].src;
    u16* dst = tt.d[e].dst;
    const int K = tt.d[e].K, N = tt.d[e].N;
    const int local = tb - tt.d[e].ofs;
    const int nx = N >> 5;
    const int bx = (local % nx) * 32;
    const int by = (local / nx) * 32;
    const int tx = threadIdx.x & 31;
    const int ty = threadIdx.x >> 5; // 0..7
#pragma unroll
    for (int i = 0; i < 32; i += 8)
        t[ty + i][tx] = f2bf(src[(size_t)(by + ty + i) * N + bx + tx]);
    __syncthreads();
#pragma unroll
    for (int i = 0; i < 32; i += 8)
        dst[(size_t)(bx + ty + i) * K + by + tx] = t[tx][ty + i];
}

// ---------------------------------------------------------------- MFMA GEMM (B^T, async staging, BK=64, xor-swizzled LDS)
// C[M,N] bf16 = A[M,K](bf16, lda) @ W[K,N] + bias[N](fp32); WT[N][K] bf16.
// BM=128, BNv in {128,64}. 4 waves, wave = 64m x (BNv/2)n; per barrier-pair: 2 k-steps.
// LDS chunk (r, s) holds global (r, s^(r&7)) -> ds_read_b128 conflict-free.
// Chunk budget: A = BM*8 = 1024 chunks (4/lane); W = BNv*8 chunks (BNv/32 per lane).
#define BM 128
#define GBK 64

template <int ACT, int BNv>
__global__ __launch_bounds__(256, 2) void gemm_bt_kernel(
    const u16* __restrict__ A, int lda, const u16* __restrict__ WT,
    const float* __restrict__ bias, u16* __restrict__ C,
    int M, int K, int N)
{
    const int NT = BNv / 32;      // n-tiles per wave
    const int WN = BNv / 2;       // n span per wave
    const int CW = BNv / 32;      // W 16B-chunks per lane (BNv*8 chunks / 256 threads)
    __shared__ __align__(16) u16 Al[BM * GBK];
    __shared__ __align__(16) u16 Wl[BNv * GBK];

    const int tid  = threadIdx.x;
    const int lane = tid & 63;
    const int w    = tid >> 6;
    const int wm = w >> 1, wn = w & 1;
    const int col = lane & 15, qq = lane >> 4;
    const size_t bm = (size_t)blockIdx.y * BM;
    const size_t bn = (size_t)blockIdx.x * BNv;

    f32x4 acc[4][NT];
#pragma unroll
    for (int mt = 0; mt < 4; mt++)
#pragma unroll
        for (int nt = 0; nt < NT; nt++) acc[mt][nt] = (f32x4){0.f, 0.f, 0.f, 0.f};

    // A: 1024 chunks; wave owns 256, lane owns 4.
    const u16* gA[4]; u16* lA[4];
#pragma unroll
    for (int i = 0; i < 4; i++) {
        int f = w * 256 + i * 64 + lane;
        int r = f >> 3, s = f & 7, sg = s ^ (r & 7);
        gA[i] = A + (bm + r) * (size_t)lda + sg * 8;
        lA[i] = &Al[(size_t)(w * 256 + i * 64) * 8];
    }
    // W: BNv*8 chunks; wave owns BNv*2, lane owns CW.
    const u16* gW[4]; u16* lW[4];
#pragma unroll
    for (int i = 0; i < CW; i++) {
        int f = w * (BNv * 2) + i * 64 + lane;
        int r = f >> 3, s = f & 7, sg = s ^ (r & 7);
        gW[i] = WT + (bn + r) * (size_t)K + sg * 8;
        lW[i] = &Wl[(size_t)(w * (BNv * 2) + i * 64) * 8];
    }

    for (int k0 = 0; k0 < K; k0 += GBK) {
#pragma unroll
        for (int i = 0; i < 4; i++) gld16(gA[i] + k0, lA[i]);
#pragma unroll
        for (int i = 0; i < CW; i++) gld16(gW[i] + k0, lW[i]);
        __syncthreads();

#pragma unroll
        for (int kk = 0; kk < 2; kk++) {
            bf16x8 af[4], bfr[NT];
#pragma unroll
            for (int mt = 0; mt < 4; mt++) {
                int rr = wm * 64 + mt * 16 + col;
                int sub = (kk * 4 + qq) ^ (rr & 7);
                af[mt] = *(const bf16x8*)&Al[rr * GBK + sub * 8];
            }
#pragma unroll
            for (int nt = 0; nt < NT; nt++) {
                int rn = wn * WN + nt * 16 + col;
                int sub = (kk * 4 + qq) ^ (rn & 7);
                bfr[nt] = *(const bf16x8*)&Wl[rn * GBK + sub * 8];
            }
#pragma unroll
            for (int mt = 0; mt < 4; mt++)
#pragma unroll
                for (int nt = 0; nt < NT; nt++)
                    acc[mt][nt] = __builtin_amdgcn_mfma_f32_16x16x32_bf16(
                        af[mt], bfr[nt], acc[mt][nt], 0, 0, 0);
        }
        __syncthreads();
    }

    float bv[NT];
#pragma unroll
    for (int nt = 0; nt < NT; nt++)
        bv[nt] = bias[bn + wn * WN + nt * 16 + col];

#pragma unroll
    for (int mt = 0; mt < 4; mt++) {
#pragma unroll
        for (int nt = 0; nt < NT; nt++) {
#pragma unroll
            for (int r = 0; r < 4; r++) {
                float v = acc[mt][nt][r] + bv[nt];
                if (ACT == 1) v = 0.5f * v * (1.0f + erff(v * 0.70710678118654752f));
                size_t rg = bm + wm * 64 + mt * 16 + qq * 4 + r;
                C[rg * (size_t)N + bn + wn * WN + nt * 16 + col] = f2bf(v);
            }
        }
    }
}

// ---------------------------------------------------------------- flash attention (MFMA)
// grid (SEQ/BQ, BATCH*HEADS); 256 thr = 4 waves; wave w owns q rows [32w, 32w+32).
// Order per tile: staged regs->LDS, barrier, bias loads (current), K/V prefetch (next),
// S=QK^T, +bias, online softmax (alpha bcast via wave-private LDS), P->LDS,
// PV with SWAPPED operands (D[m=d][n=q]) -> packed O epilogue.
#define BQ  128
#define BKV 128
#define LDK 72
#define LDP 136

__global__ __launch_bounds__(256, 2) void fattn_kernel(
    const u16* __restrict__ Q, const u16* __restrict__ K,
    const u16* __restrict__ V, const float* __restrict__ abP,
    u16* __restrict__ O)
{
    __shared__ __align__(16) u16 Ks[BKV * LDK];   // 18,432 B
    __shared__ __align__(16) u16 Ps[BQ * LDP];    // 34,816 B
    __shared__ __align__(16) u16 Vt[HD * LDP];    // 17,408 B
    __shared__ float bc_s[4][32];                 // alpha / l broadcast (wave-private rows)

    const int tid = threadIdx.x;
    const int lane = tid & 63;
    const int w = tid >> 6;
    const int col = lane & 15, qq = lane >> 4;
    const int qt = blockIdx.x;                    // 0..15
    const int b = blockIdx.y >> 4, h = blockIdx.y & 15;
    const size_t tok0 = (size_t)b * SEQ + (size_t)qt * BQ;
    const int wrow = w * 32;
    const size_t kvbase = (size_t)b * SEQ * EMB + h * HD;
    const int jq = tid & 31, dg = tid >> 5;

    // Q fragments in registers (A-layout)
    bf16x8 aq[2][2];
#pragma unroll
    for (int mt = 0; mt < 2; mt++)
#pragma unroll
        for (int kk = 0; kk < 2; kk++)
            aq[mt][kk] = *(const bf16x8*)(Q + (tok0 + wrow + mt * 16 + col) * EMB
                                          + h * HD + kk * 32 + qq * 8);

    float m_st[2][4], l_st[2][4];
    f32x4 o_acc[2][4];   // [mt(q-tile)][dt(d-tile)]; rows = d (qq*4+r), cols = q (col)
#pragma unroll
    for (int mt = 0; mt < 2; mt++)
#pragma unroll
        for (int r = 0; r < 4; r++) { m_st[mt][r] = -1e30f; l_st[mt][r] = 0.f; }
#pragma unroll
    for (int mt = 0; mt < 2; mt++)
#pragma unroll
        for (int dt = 0; dt < 4; dt++) o_acc[mt][dt] = (f32x4){0.f, 0.f, 0.f, 0.f};

    uint4 kreg[4], vreg[4];
#define LOADKV(KV0) do {                                                             \
        _Pragma("unroll")                                                            \
        for (int i = 0; i < 4; i++) {                                                \
            int c = tid + i * 256;                                                   \
            kreg[i] = *(const uint4*)(K + kvbase + (size_t)((KV0) + (c >> 3)) * EMB  \
                                      + (c & 7) * 8);                                \
        }                                                                            \
        _Pragma("unroll")                                                            \
        for (int i = 0; i < 4; i++)                                                  \
            vreg[i] = *(const uint4*)(V + kvbase + (size_t)((KV0) + jq * 4 + i) * EMB\
                                      + dg * 8);                                     \
    } while (0)

    LOADKV(0);

    for (int t = 0; t < SEQ / BKV; t++) {
        // staged regs -> LDS
#pragma unroll
        for (int i = 0; i < 4; i++) {
            int c = tid + i * 256;
            *(uint4*)&Ks[(c >> 3) * LDK + (c & 7) * 8] = kreg[i];
        }
        {
            u16 vv[4][8];
#pragma unroll
            for (int i = 0; i < 4; i++) *(uint4*)vv[i] = vreg[i];
#pragma unroll
            for (int dd = 0; dd < 8; dd++) {
                ushort4 w4; w4.x = vv[0][dd]; w4.y = vv[1][dd]; w4.z = vv[2][dd]; w4.w = vv[3][dd];
                *(ushort4*)&Vt[(dg * 8 + dd) * LDP + jq * 4] = w4;
            }
        }
        __syncthreads();

        // current-tile bias loads FIRST (older in vmcnt order -> waiting on them
        // leaves the K/V prefetch below in flight)
        const float* abb = abP + (((size_t)qt * 16 + t) * 4 + w) * 4096;
        float4 abv[2][8];
#pragma unroll
        for (int mt = 0; mt < 2; mt++)
#pragma unroll
            for (int nt = 0; nt < 8; nt++)
                abv[mt][nt] = *(const float4*)(abb + (mt * 8 + nt) * 256 + lane * 4);

        // prefetch next tile's K/V
        if (t + 1 < SEQ / BKV) LOADKV((t + 1) * BKV);

        // S = Q K^T
        f32x4 s[2][8];
#pragma unroll
        for (int nt = 0; nt < 8; nt++) {
            bf16x8 bk0 = *(const bf16x8*)&Ks[(nt * 16 + col) * LDK + qq * 8];
            bf16x8 bk1 = *(const bf16x8*)&Ks[(nt * 16 + col) * LDK + 32 + qq * 8];
#pragma unroll
            for (int mt = 0; mt < 2; mt++) {
                f32x4 acc0 = (f32x4){0.f, 0.f, 0.f, 0.f};
                acc0 = __builtin_amdgcn_mfma_f32_16x16x32_bf16(aq[mt][0], bk0, acc0, 0, 0, 0);
                acc0 = __builtin_amdgcn_mfma_f32_16x16x32_bf16(aq[mt][1], bk1, acc0, 0, 0, 0);
                s[mt][nt] = acc0;
            }
        }
        // scale + bias
#pragma unroll
        for (int mt = 0; mt < 2; mt++)
#pragma unroll
            for (int nt = 0; nt < 8; nt++) {
                s[mt][nt][0] = fmaf(s[mt][nt][0], 0.125f, abv[mt][nt].x);
                s[mt][nt][1] = fmaf(s[mt][nt][1], 0.125f, abv[mt][nt].y);
                s[mt][nt][2] = fmaf(s[mt][nt][2], 0.125f, abv[mt][nt].z);
                s[mt][nt][3] = fmaf(s[mt][nt][3], 0.125f, abv[mt][nt].w);
            }

        // online softmax (exp in place); alpha broadcast for q=col consumers
#pragma unroll
        for (int mt = 0; mt < 2; mt++)
#pragma unroll
            for (int r = 0; r < 4; r++) {
                float tm = s[mt][0][r];
#pragma unroll
                for (int nt = 1; nt < 8; nt++) tm = fmaxf(tm, s[mt][nt][r]);
#pragma unroll
                for (int msk = 1; msk < 16; msk <<= 1) tm = fmaxf(tm, __shfl_xor(tm, msk));
                float mnew = fmaxf(m_st[mt][r], tm);
                float al = __expf(m_st[mt][r] - mnew);
                m_st[mt][r] = mnew;
                float rs = 0.f;
#pragma unroll
                for (int nt = 0; nt < 8; nt++) {
                    float e = __expf(s[mt][nt][r] - mnew);
                    s[mt][nt][r] = e;
                    rs += e;
                }
#pragma unroll
                for (int msk = 1; msk < 16; msk <<= 1) rs += __shfl_xor(rs, msk);
                l_st[mt][r] = l_st[mt][r] * al + rs;
                if (col == 0) bc_s[w][mt * 16 + qq * 4 + r] = al;
            }
        float a2[2];
#pragma unroll
        for (int mt = 0; mt < 2; mt++) a2[mt] = bc_s[w][mt * 16 + col];
#pragma unroll
        for (int mt = 0; mt < 2; mt++)
#pragma unroll
            for (int dt = 0; dt < 4; dt++)
#pragma unroll
                for (int r = 0; r < 4; r++) o_acc[mt][dt][r] *= a2[mt];

        // P write [q][k] (wave-private rows; same-wave LDS RAW is in-order)
#pragma unroll
        for (int mt = 0; mt < 2; mt++)
#pragma unroll
            for (int nt = 0; nt < 8; nt++)
#pragma unroll
                for (int r = 0; r < 4; r++)
                    Ps[(wrow + mt * 16 + qq * 4 + r) * LDP + nt * 16 + col] = f2bf(s[mt][nt][r]);

        // O^T accumulate: mfma(A=V^T frag, B=P frag) -> D[m=d][n=q]
#pragma unroll
        for (int kk = 0; kk < 4; kk++) {
            bf16x8 pb[2];
#pragma unroll
            for (int mt = 0; mt < 2; mt++)
                pb[mt] = *(const bf16x8*)&Ps[(wrow + mt * 16 + col) * LDP + kk * 32 + qq * 8];
#pragma unroll
            for (int dt = 0; dt < 4; dt++) {
                bf16x8 va = *(const bf16x8*)&Vt[(dt * 16 + col) * LDP + kk * 32 + qq * 8];
                o_acc[0][dt] = __builtin_amdgcn_mfma_f32_16x16x32_bf16(va, pb[0], o_acc[0][dt], 0, 0, 0);
                o_acc[1][dt] = __builtin_amdgcn_mfma_f32_16x16x32_bf16(va, pb[1], o_acc[1][dt], 0, 0, 0);
            }
        }
        __syncthreads();   // Ks/Vt/Ps reads done before next staging overwrite
    }
#undef LOADKV

    // epilogue: l broadcast, packed O stores (r consecutive in d)
    if (col == 0) {
#pragma unroll
        for (int mt = 0; mt < 2; mt++)
#pragma unroll
            for (int r = 0; r < 4; r++) bc_s[w][mt * 16 + qq * 4 + r] = l_st[mt][r];
    }
    float linv[2];
#pragma unroll
    for (int mt = 0; mt < 2; mt++) linv[mt] = 1.0f / bc_s[w][mt * 16 + col];
#pragma unroll
    for (int mt = 0; mt < 2; mt++)
#pragma unroll
        for (int dt = 0; dt < 4; dt++) {
            ushort4 o4;
            o4.x = f2bf(o_acc[mt][dt][0] * linv[mt]);
            o4.y = f2bf(o_acc[mt][dt][1] * linv[mt]);
            o4.z = f2bf(o_acc[mt][dt][2] * linv[mt]);
            o4.w = f2bf(o_acc[mt][dt][3] * linv[mt]);
            *(ushort4*)(O + (tok0 + wrow + mt * 16 + col) * EMB + h * HD + dt * 16 + qq * 4) = o4;
        }
}

// ---------------------------------------------------------------- residual + LayerNorm
template <int AF32, int OUTF32>
__global__ __launch_bounds__(256) void ln_kernel(
    const void* __restrict__ A, const u16* __restrict__ R,
    const float* __restrict__ w, const float* __restrict__ bb,
    void* __restrict__ out)
{
    __shared__ float r1[4], r2[4];
    const int tid = threadIdx.x;
    const size_t row = blockIdx.x;

    float v[4];
    float s = 0.0f, s2 = 0.0f;
#pragma unroll
    for (int i = 0; i < 4; i++) {
        int c = tid + i * 256;
        float a = AF32 ? ((const float*)A)[row * EMB + c]
                       : bf2f(((const u16*)A)[row * EMB + c]);
        float t = a + bf2f(R[row * EMB + c]);
        v[i] = t;
        s += t; s2 += t * t;
    }
#pragma unroll
    for (int o = 32; o > 0; o >>= 1) {
        s  += __shfl_down(s, o);
        s2 += __shfl_down(s2, o);
    }
    if ((tid & 63) == 0) { r1[tid >> 6] = s; r2[tid >> 6] = s2; }
    __syncthreads();
    s  = r1[0] + r1[1] + r1[2] + r1[3];
    s2 = r2[0] + r2[1] + r2[2] + r2[3];

    float mu = s * (1.0f / EMB);
    float var = s2 * (1.0f / EMB) - mu * mu;
    float rs = rsqrtf(var + 1e-5f);

#pragma unroll
    for (int i = 0; i < 4; i++) {
        int c = tid + i * 256;
        float y = (v[i] - mu) * rs * w[c] + bb[c];
        if (OUTF32) ((float*)out)[row * EMB + c] = y;
        else        ((u16*)out)[row * EMB + c] = f2bf(y);
    }
}

// ---------------------------------------------------------------- launch
extern "C" void kernel_launch(void* const* d_in, const int* in_sizes, int n_in,
                              void* d_out, int out_size, void* d_ws, size_t ws_size,
                              hipStream_t stream)
{
    const float* x    = (const float*)d_in[0];
    const float* ab   = (const float*)d_in[1];
    const float* Wq   = (const float*)d_in[2];
    const float* bq   = (const float*)d_in[3];
    const float* WaK  = (const float*)d_in[4];
    const float* baK  = (const float*)d_in[5];
    const float* WbK  = (const float*)d_in[6];
    const float* bbK  = (const float*)d_in[7];
    const float* WaV  = (const float*)d_in[8];
    const float* baV  = (const float*)d_in[9];
    const float* WbV  = (const float*)d_in[10];
    const float* bbV  = (const float*)d_in[11];
    const float* Wo   = (const float*)d_in[12];
    const float* bo   = (const float*)d_in[13];
    const float* W1   = (const float*)d_in[14];
    const float* b1   = (const float*)d_in[15];
    const float* W2   = (const float*)d_in[16];
    const float* b2   = (const float*)d_in[17];
    const float* ln1w = (const float*)d_in[18];
    const float* ln1b = (const float*)d_in[19];
    const float* ln2w = (const float*)d_in[20];
    const float* ln2b = (const float*)d_in[21];

    u16* w = (u16*)d_ws;
    size_t o = 0;
    u16* WqT  = w + o; o += (size_t)EMB * EMB;
    u16* WaKT = w + o; o += (size_t)EMB * LATD;    // WaKT+WaVT contiguous = combined WT
    u16* WaVT = w + o; o += (size_t)EMB * LATD;
    u16* WbKT = w + o; o += (size_t)LATD * EMB;
    u16* WbVT = w + o; o += (size_t)LATD * EMB;
    u16* WoT  = w + o; o += (size_t)EMB * EMB;
    u16* W1T  = w + o; o += (size_t)EMB * FFND;
    u16* W2T  = w + o; o += (size_t)FFND * EMB;
    u16* Qb   = w + o; o += (size_t)TOK * EMB;
    u16* Kb   = w + o; o += (size_t)TOK * EMB;
    u16* Vb   = w + o; o += (size_t)TOK * EMB;
    u16* aOb  = w + o; o += (size_t)TOK * EMB;
    u16* projb= w + o; o += (size_t)TOK * EMB;
    u16* hb   = w + o; o += (size_t)TOK * EMB;
    u16* xb   = w + o; o += (size_t)TOK * EMB;     // bf16 x (own slot)
    float* bKV = (float*)(w + o); o += 1024;       // 512 fp32 concat bias
    // overlays (non-overlapping lifetimes):
    float* abP = (float*)projb;               // 16 MiB = projb+hb exactly; dead after fattn
    u16* KVa = aOb;                           // [TOK][512]; dead before fattn writes aOb
    u16* f1  = Qb;                            // spans Qb..aOb = TOK*FFND
    u16* f2  = projb;                         // abP/proj dead after ln1

    dim3 blk(256);

    cvt_f32_bf16_kernel<<<dim3(2048), blk, 0, stream>>>(x, xb, TOK * EMB / 8);
    concat_bias_kernel<<<dim3(2), blk, 0, stream>>>(baK, baV, bKV);
    permute_ab_kernel<<<dim3(16, 16), blk, 0, stream>>>(ab, abP);

    // merged weight transposes (tiles: 1024,256,256,256,256,1024,4096,4096 = 11264)
    TTable tt;
    tt.d[0] = {Wq,  WqT,  EMB,  EMB,  0};
    tt.d[1] = {WaK, WaKT, EMB,  LATD, 1024};
    tt.d[2] = {WaV, WaVT, EMB,  LATD, 1280};
    tt.d[3] = {WbK, WbKT, LATD, EMB,  1536};
    tt.d[4] = {WbV, WbVT, LATD, EMB,  1792};
    tt.d[5] = {Wo,  WoT,  EMB,  EMB,  2048};
    tt.d[6] = {W1,  W1T,  EMB,  FFND, 3072};
    tt.d[7] = {W2,  W2T,  FFND, EMB,  7168};
    transpose_all_kernel<<<dim3(11264), blk, 0, stream>>>(tt);

    // Q = x @ Wq + bq                                  (512 blocks)
    gemm_bt_kernel<0,64><<<dim3(EMB / 64, TOK / BM), blk, 0, stream>>>(xb, EMB, WqT, bq, Qb, TOK, EMB, EMB);
    // [Ka|Va] = x @ [WaK|WaV] + [baK|baV]              (256 blocks)
    gemm_bt_kernel<0,64><<<dim3(512 / 64, TOK / BM), blk, 0, stream>>>(xb, EMB, WaKT, bKV, KVa, TOK, EMB, 512);
    // K = Ka @ WbK + bbK ; V = Va @ WbV + bbV          (512 blocks each)
    gemm_bt_kernel<0,64><<<dim3(EMB / 64, TOK / BM), blk, 0, stream>>>(KVa, 512, WbKT, bbK, Kb, TOK, LATD, EMB);
    gemm_bt_kernel<0,64><<<dim3(EMB / 64, TOK / BM), blk, 0, stream>>>(KVa + LATD, 512, WbVT, bbV, Vb, TOK, LATD, EMB);

    // flash attention -> aOb                           (512 blocks)
    fattn_kernel<<<dim3(SEQ / BQ, BATCH * HEADS), blk, 0, stream>>>(Qb, Kb, Vb, abP, aOb);

    // proj = aO @ Wo + bo                              (512 blocks)
    gemm_bt_kernel<0,64><<<dim3(EMB / 64, TOK / BM), blk, 0, stream>>>(aOb, EMB, WoT, bo, projb, TOK, EMB, EMB);

    // h = LN(x + proj) -> bf16 hb
    ln_kernel<1,0><<<dim3(TOK), blk, 0, stream>>>(x, projb, ln1w, ln1b, hb);

    // f1 = gelu(h @ W1 + b1)                           (1024 blocks)
    gemm_bt_kernel<1,128><<<dim3(FFND / 128, TOK / BM), blk, 0, stream>>>(hb, EMB, W1T, b1, f1, TOK, EMB, FFND);
    // f2 = f1 @ W2 + b2                                (512 blocks)
    gemm_bt_kernel<0,64><<<dim3(EMB / 64, TOK / BM), blk, 0, stream>>>(f1, FFND, W2T, b2, f2, TOK, FFND, EMB);

    // out = LN(h + f2) -> fp32 d_out
    ln_kernel<0,1><<<dim3(TOK), blk, 0, stream>>>(hb, f2, ln2w, ln2b, (float*)d_out);
}

// Round 9
// 447.489 us; speedup vs baseline: 12.8413x; 1.0214x over previous
//
#include <hip/hip_runtime.h>
#include <hip/hip_bf16.h>
#include <math.h>

typedef unsigned short u16;
typedef short bf16x8 __attribute__((ext_vector_type(8)));
typedef float f32x4 __attribute__((ext_vector_type(4)));

#define EMB   1024
#define HEADS 16
#define HD    64
#define LATD  256
#define FFND  4096
#define BATCH 2
#define SEQ   2048
#define TOK   (BATCH*SEQ)   // 4096

__device__ __forceinline__ float bf2f(u16 u) {
    union { unsigned int i; float f; } x; x.i = ((unsigned int)u) << 16; return x.f;
}
__device__ __forceinline__ u16 f2bf(float f) {
    union { float f; unsigned int i; } x; x.f = f;
    unsigned int i = x.i;
    unsigned int lsb = (i >> 16) & 1u;
    i += 0x7fffu + lsb;       // round-to-nearest-even
    return (u16)(i >> 16);
}
__device__ __forceinline__ void gld16(const u16* g, u16* l) {
    __builtin_amdgcn_global_load_lds(
        (const __attribute__((address_space(1))) void*)g,
        (__attribute__((address_space(3))) void*)l, 16, 0, 0);
}

// ---------------------------------------------------------------- fp32 -> bf16 convert
__global__ __launch_bounds__(256) void cvt_f32_bf16_kernel(
    const float* __restrict__ in, u16* __restrict__ out, int n8)
{
    int i = blockIdx.x * 256 + threadIdx.x;
    int stride = gridDim.x * 256;
    for (; i < n8; i += stride) {
        float4 f0 = *(const float4*)(in + (size_t)i * 8);
        float4 f1 = *(const float4*)(in + (size_t)i * 8 + 4);
        u16 e[8];
        e[0] = f2bf(f0.x); e[1] = f2bf(f0.y); e[2] = f2bf(f0.z); e[3] = f2bf(f0.w);
        e[4] = f2bf(f1.x); e[5] = f2bf(f1.y); e[6] = f2bf(f1.z); e[7] = f2bf(f1.w);
        *(uint4*)(out + (size_t)i * 8) = *(const uint4*)e;
    }
}

// ---------------------------------------------------------------- concat 2 bias vectors (256 each)
__global__ __launch_bounds__(256) void concat_bias_kernel(
    const float* __restrict__ a, const float* __restrict__ b, float* __restrict__ out)
{
    int i = blockIdx.x * 256 + threadIdx.x;   // 0..511
    out[i] = (i < 256) ? a[i] : b[i - 256];
}

// ---------------------------------------------------------------- permute attn_bias into MFMA C-frag order
// abP[qt][kt][w][mt][nt][lane][r], fp32. grid (16 kt, 16 qt), 256 thr.
__global__ __launch_bounds__(256) void permute_ab_kernel(
    const float* __restrict__ ab, float* __restrict__ abP)
{
    const int kt = blockIdx.x, qt = blockIdx.y;
    const int tid = threadIdx.x;
    const int w = tid >> 6, lane = tid & 63, qq = (lane >> 4), col = lane & 15;
    float* out = abP + ((size_t)qt * 16 + kt) * 16384 + (size_t)w * 4096;
#pragma unroll
    for (int mt = 0; mt < 2; mt++)
#pragma unroll
        for (int nt = 0; nt < 8; nt++) {
            float4 v;
            const float* src = ab + (size_t)(qt * 128 + w * 32 + mt * 16 + qq * 4) * SEQ
                               + kt * 128 + nt * 16 + col;
            v.x = src[0]; v.y = src[SEQ]; v.z = src[2 * SEQ]; v.w = src[3 * SEQ];
            *(float4*)(out + ((mt * 8 + nt) * 256) + lane * 4) = v;
        }
}

// ---------------------------------------------------------------- merged transpose+cvt (8 matrices)
struct TDesc { const float* src; u16* dst; int K; int N; int ofs; };
struct TTable { TDesc d[8]; };

__global__ __launch_bounds__(256) void transpose_all_kernel(TTable tt)
{
    __shared__ u16 t[32][33];
    int tb = blockIdx.x, e = 0;
#pragma unroll
    for (int i = 1; i < 8; i++) if (tb >= tt.d[i].ofs) e = i;
    const float* src = tt.d[e].src;
    u16* dst = tt.d[e].dst;
    const int K = tt.d[e].K, N = tt.d[e].N;
    const int local = tb - tt.d[e].ofs;
    const int nx = N >> 5;
    const int bx = (local % nx) * 32;
    const int by = (local / nx) * 32;
    const int tx = threadIdx.x & 31;
    const int ty = threadIdx.x >> 5; // 0..7
#pragma unroll
    for (int i = 0; i < 32; i += 8)
        t[ty + i][tx] = f2bf(src[(size_t)(by + ty + i) * N + bx + tx]);
    __syncthreads();
#pragma unroll
    for (int i = 0; i < 32; i += 8)
        dst[(size_t)(bx + ty + i) * K + by + tx] = t[tx][ty + i];
}

// ---------------------------------------------------------------- MFMA GEMM body (B^T, async staging, BK=64, xor-swizzled LDS)
// C[M,N] bf16 = A[.,K](bf16, lda) @ W[K,N] + bias[N](fp32); WT[N][K] bf16.
// BM=128, BNv in {128,64}. 4 waves, wave = 64m x (BNv/2)n; per barrier-pair: 2 k-steps.
// LDS chunk (r, s) holds global (r, s^(r&7)) -> conflict-optimal ds_read_b128.
#define BM 128
#define GBK 64

template <int ACT, int BNv>
__device__ __forceinline__ void gemm_body(
    const u16* __restrict__ A, int lda, const u16* __restrict__ WT,
    const float* __restrict__ bias, u16* __restrict__ C,
    int K, int N, int bx, u16* Al, u16* Wl)
{
    const int NT = BNv / 32;
    const int WN = BNv / 2;
    const int CW = BNv / 32;      // W 16B-chunks per lane (BNv*8 / 256)

    const int tid  = threadIdx.x;
    const int lane = tid & 63;
    const int w    = tid >> 6;
    const int wm = w >> 1, wn = w & 1;
    const int col = lane & 15, qq = lane >> 4;
    const size_t bm = (size_t)blockIdx.y * BM;
    const size_t bn = (size_t)bx * BNv;

    f32x4 acc[4][NT];
#pragma unroll
    for (int mt = 0; mt < 4; mt++)
#pragma unroll
        for (int nt = 0; nt < NT; nt++) acc[mt][nt] = (f32x4){0.f, 0.f, 0.f, 0.f};

    const u16* gA[4]; u16* lA[4];
#pragma unroll
    for (int i = 0; i < 4; i++) {
        int f = w * 256 + i * 64 + lane;
        int r = f >> 3, s = f & 7, sg = s ^ (r & 7);
        gA[i] = A + (bm + r) * (size_t)lda + sg * 8;
        lA[i] = &Al[(size_t)(w * 256 + i * 64) * 8];
    }
    const u16* gW[4]; u16* lW[4];
#pragma unroll
    for (int i = 0; i < CW; i++) {
        int f = w * (BNv * 2) + i * 64 + lane;
        int r = f >> 3, s = f & 7, sg = s ^ (r & 7);
        gW[i] = WT + (bn + r) * (size_t)K + sg * 8;
        lW[i] = &Wl[(size_t)(w * (BNv * 2) + i * 64) * 8];
    }

    for (int k0 = 0; k0 < K; k0 += GBK) {
#pragma unroll
        for (int i = 0; i < 4; i++) gld16(gA[i] + k0, lA[i]);
#pragma unroll
        for (int i = 0; i < CW; i++) gld16(gW[i] + k0, lW[i]);
        __syncthreads();

#pragma unroll
        for (int kk = 0; kk < 2; kk++) {
            bf16x8 af[4], bfr[NT];
#pragma unroll
            for (int mt = 0; mt < 4; mt++) {
                int rr = wm * 64 + mt * 16 + col;
                int sub = (kk * 4 + qq) ^ (rr & 7);
                af[mt] = *(const bf16x8*)&Al[rr * GBK + sub * 8];
            }
#pragma unroll
            for (int nt = 0; nt < NT; nt++) {
                int rn = wn * WN + nt * 16 + col;
                int sub = (kk * 4 + qq) ^ (rn & 7);
                bfr[nt] = *(const bf16x8*)&Wl[rn * GBK + sub * 8];
            }
#pragma unroll
            for (int mt = 0; mt < 4; mt++)
#pragma unroll
                for (int nt = 0; nt < NT; nt++)
                    acc[mt][nt] = __builtin_amdgcn_mfma_f32_16x16x32_bf16(
                        af[mt], bfr[nt], acc[mt][nt], 0, 0, 0);
        }
        __syncthreads();
    }

    float bv[NT];
#pragma unroll
    for (int nt = 0; nt < NT; nt++)
        bv[nt] = bias[bn + wn * WN + nt * 16 + col];

#pragma unroll
    for (int mt = 0; mt < 4; mt++) {
#pragma unroll
        for (int nt = 0; nt < NT; nt++) {
#pragma unroll
            for (int r = 0; r < 4; r++) {
                float v = acc[mt][nt][r] + bv[nt];
                if (ACT == 1) v = 0.5f * v * (1.0f + erff(v * 0.70710678118654752f));
                size_t rg = bm + wm * 64 + mt * 16 + qq * 4 + r;
                C[rg * (size_t)N + bn + wn * WN + nt * 16 + col] = f2bf(v);
            }
        }
    }
}

// plain single-segment GEMM
template <int ACT, int BNv, int MINW>
__global__ __launch_bounds__(256, MINW) void gemm_bt_kernel(
    const u16* __restrict__ A, int lda, const u16* __restrict__ WT,
    const float* __restrict__ bias, u16* __restrict__ C,
    int K, int N)
{
    __shared__ __align__(16) u16 Al[BM * GBK];
    __shared__ __align__(16) u16 Wl[BNv * GBK];
    gemm_body<ACT, BNv>(A, lda, WT, bias, C, K, N, blockIdx.x, Al, Wl);
}

// two-segment merged GEMM (same K both segments)
struct GPair {
    const u16* A0; const u16* A1;
    const u16* W0; const u16* W1;
    const float* b0; const float* b1;
    u16* C0; u16* C1;
    int lda0, lda1, N0, N1, nx0;
};

template <int BNv, int MINW>
__global__ __launch_bounds__(256, MINW) void gemm_pair_kernel(GPair p, int K)
{
    __shared__ __align__(16) u16 Al[BM * GBK];
    __shared__ __align__(16) u16 Wl[BNv * GBK];
    const bool s1 = (int)blockIdx.x >= p.nx0;
    const u16* A = s1 ? p.A1 : p.A0;
    const u16* WT = s1 ? p.W1 : p.W0;
    const float* bias = s1 ? p.b1 : p.b0;
    u16* C = s1 ? p.C1 : p.C0;
    const int lda = s1 ? p.lda1 : p.lda0;
    const int N = s1 ? p.N1 : p.N0;
    const int bx = s1 ? (int)blockIdx.x - p.nx0 : (int)blockIdx.x;
    gemm_body<0, BNv>(A, lda, WT, bias, C, K, N, bx, Al, Wl);
}

// ---------------------------------------------------------------- flash attention (MFMA) — R6 version (best measured)
// grid (SEQ/BQ, BATCH*HEADS); 256 thr = 4 waves; wave w owns q rows [32w, 32w+32).
#define BQ  128
#define BKV 128
#define LDK 72
#define LDP 136

__global__ __launch_bounds__(256, 2) void fattn_kernel(
    const u16* __restrict__ Q, const u16* __restrict__ K,
    const u16* __restrict__ V, const float* __restrict__ abP,
    u16* __restrict__ O)
{
    __shared__ __align__(16) u16 Ks[BKV * LDK];   // 18,432 B
    __shared__ __align__(16) u16 Ps[BQ * LDP];    // 34,816 B
    __shared__ __align__(16) u16 Vt[HD * LDP];    // 17,408 B

    const int tid = threadIdx.x;
    const int lane = tid & 63;
    const int w = tid >> 6;
    const int col = lane & 15, qq = lane >> 4;
    const int qt = blockIdx.x;                    // 0..15
    const int b = blockIdx.y >> 4, h = blockIdx.y & 15;
    const size_t tok0 = (size_t)b * SEQ + (size_t)qt * BQ;
    const int wrow = w * 32;
    const size_t kvbase = (size_t)b * SEQ * EMB + h * HD;
    const int jq = tid & 31, dg = tid >> 5;

    bf16x8 aq[2][2];
#pragma unroll
    for (int mt = 0; mt < 2; mt++)
#pragma unroll
        for (int kk = 0; kk < 2; kk++)
            aq[mt][kk] = *(const bf16x8*)(Q + (tok0 + wrow + mt * 16 + col) * EMB
                                          + h * HD + kk * 32 + qq * 8);

    float m_st[2][4], l_st[2][4];
    f32x4 o_acc[2][4];
#pragma unroll
    for (int mt = 0; mt < 2; mt++)
#pragma unroll
        for (int r = 0; r < 4; r++) { m_st[mt][r] = -1e30f; l_st[mt][r] = 0.f; }
#pragma unroll
    for (int mt = 0; mt < 2; mt++)
#pragma unroll
        for (int dt = 0; dt < 4; dt++) o_acc[mt][dt] = (f32x4){0.f, 0.f, 0.f, 0.f};

    uint4 kreg[4], vreg[4];
#define LOADKV(KV0) do {                                                             \
        _Pragma("unroll")                                                            \
        for (int i = 0; i < 4; i++) {                                                \
            int c = tid + i * 256;                                                   \
            kreg[i] = *(const uint4*)(K + kvbase + (size_t)((KV0) + (c >> 3)) * EMB  \
                                      + (c & 7) * 8);                                \
        }                                                                            \
        _Pragma("unroll")                                                            \
        for (int i = 0; i < 4; i++)                                                  \
            vreg[i] = *(const uint4*)(V + kvbase + (size_t)((KV0) + jq * 4 + i) * EMB\
                                      + dg * 8);                                     \
    } while (0)

    LOADKV(0);

    for (int t = 0; t < SEQ / BKV; t++) {
#pragma unroll
        for (int i = 0; i < 4; i++) {
            int c = tid + i * 256;
            *(uint4*)&Ks[(c >> 3) * LDK + (c & 7) * 8] = kreg[i];
        }
        {
            u16 vv[4][8];
#pragma unroll
            for (int i = 0; i < 4; i++) *(uint4*)vv[i] = vreg[i];
#pragma unroll
            for (int dd = 0; dd < 8; dd++) {
                ushort4 w4; w4.x = vv[0][dd]; w4.y = vv[1][dd]; w4.z = vv[2][dd]; w4.w = vv[3][dd];
                *(ushort4*)&Vt[(dg * 8 + dd) * LDP + jq * 4] = w4;
            }
        }
        __syncthreads();

        // prefetch next tile's K/V while computing this one
        if (t + 1 < SEQ / BKV) LOADKV((t + 1) * BKV);

        // bias fragments: 16 coalesced float4 loads
        const float* abb = abP + (((size_t)qt * 16 + t) * 4 + w) * 4096;
        float4 abv[2][8];
#pragma unroll
        for (int mt = 0; mt < 2; mt++)
#pragma unroll
            for (int nt = 0; nt < 8; nt++)
                abv[mt][nt] = *(const float4*)(abb + (mt * 8 + nt) * 256 + lane * 4);

        // S = Q K^T
        f32x4 s[2][8];
#pragma unroll
        for (int nt = 0; nt < 8; nt++) {
            bf16x8 bk0 = *(const bf16x8*)&Ks[(nt * 16 + col) * LDK + qq * 8];
            bf16x8 bk1 = *(const bf16x8*)&Ks[(nt * 16 + col) * LDK + 32 + qq * 8];
#pragma unroll
            for (int mt = 0; mt < 2; mt++) {
                f32x4 acc0 = (f32x4){0.f, 0.f, 0.f, 0.f};
                acc0 = __builtin_amdgcn_mfma_f32_16x16x32_bf16(aq[mt][0], bk0, acc0, 0, 0, 0);
                acc0 = __builtin_amdgcn_mfma_f32_16x16x32_bf16(aq[mt][1], bk1, acc0, 0, 0, 0);
                s[mt][nt] = acc0;
            }
        }
        // scale + bias
#pragma unroll
        for (int mt = 0; mt < 2; mt++)
#pragma unroll
            for (int nt = 0; nt < 8; nt++) {
                s[mt][nt][0] = fmaf(s[mt][nt][0], 0.125f, abv[mt][nt].x);
                s[mt][nt][1] = fmaf(s[mt][nt][1], 0.125f, abv[mt][nt].y);
                s[mt][nt][2] = fmaf(s[mt][nt][2], 0.125f, abv[mt][nt].z);
                s[mt][nt][3] = fmaf(s[mt][nt][3], 0.125f, abv[mt][nt].w);
            }

        // online softmax (exp in place), per-lane alpha
        float alpha[2][4];
#pragma unroll
        for (int mt = 0; mt < 2; mt++)
#pragma unroll
            for (int r = 0; r < 4; r++) {
                float tm = s[mt][0][r];
#pragma unroll
                for (int nt = 1; nt < 8; nt++) tm = fmaxf(tm, s[mt][nt][r]);
#pragma unroll
                for (int msk = 1; msk < 16; msk <<= 1) tm = fmaxf(tm, __shfl_xor(tm, msk));
                float mnew = fmaxf(m_st[mt][r], tm);
                alpha[mt][r] = __expf(m_st[mt][r] - mnew);
                m_st[mt][r] = mnew;
                float rs = 0.f;
#pragma unroll
                for (int nt = 0; nt < 8; nt++) {
                    float e = __expf(s[mt][nt][r] - mnew);
                    s[mt][nt][r] = e;
                    rs += e;
                }
#pragma unroll
                for (int msk = 1; msk < 16; msk <<= 1) rs += __shfl_xor(rs, msk);
                l_st[mt][r] = l_st[mt][r] * alpha[mt][r] + rs;
            }
#pragma unroll
        for (int mt = 0; mt < 2; mt++)
#pragma unroll
            for (int dt = 0; dt < 4; dt++)
#pragma unroll
                for (int r = 0; r < 4; r++) o_acc[mt][dt][r] *= alpha[mt][r];

        // P write (wave-private rows; same-wave LDS RAW is in-order)
#pragma unroll
        for (int mt = 0; mt < 2; mt++)
#pragma unroll
            for (int nt = 0; nt < 8; nt++)
#pragma unroll
                for (int r = 0; r < 4; r++)
                    Ps[(wrow + mt * 16 + qq * 4 + r) * LDP + nt * 16 + col] = f2bf(s[mt][nt][r]);

        // O += P @ V
#pragma unroll
        for (int kk = 0; kk < 4; kk++) {
            bf16x8 ap0 = *(const bf16x8*)&Ps[(wrow + col) * LDP + kk * 32 + qq * 8];
            bf16x8 ap1 = *(const bf16x8*)&Ps[(wrow + 16 + col) * LDP + kk * 32 + qq * 8];
#pragma unroll
            for (int dt = 0; dt < 4; dt++) {
                bf16x8 bv = *(const bf16x8*)&Vt[(dt * 16 + col) * LDP + kk * 32 + qq * 8];
                o_acc[0][dt] = __builtin_amdgcn_mfma_f32_16x16x32_bf16(ap0, bv, o_acc[0][dt], 0, 0, 0);
                o_acc[1][dt] = __builtin_amdgcn_mfma_f32_16x16x32_bf16(ap1, bv, o_acc[1][dt], 0, 0, 0);
            }
        }
        __syncthreads();
    }
#undef LOADKV

    // epilogue
#pragma unroll
    for (int mt = 0; mt < 2; mt++)
#pragma unroll
        for (int r = 0; r < 4; r++) {
            float inv = 1.0f / l_st[mt][r];
#pragma unroll
            for (int dt = 0; dt < 4; dt++)
                O[(tok0 + wrow + mt * 16 + qq * 4 + r) * EMB + h * HD + dt * 16 + col]
                    = f2bf(o_acc[mt][dt][r] * inv);
        }
}

// ---------------------------------------------------------------- residual + LayerNorm
template <int AF32, int OUTF32>
__global__ __launch_bounds__(256) void ln_kernel(
    const void* __restrict__ A, const u16* __restrict__ R,
    const float* __restrict__ w, const float* __restrict__ bb,
    void* __restrict__ out)
{
    __shared__ float r1[4], r2[4];
    const int tid = threadIdx.x;
    const size_t row = blockIdx.x;

    float v[4];
    float s = 0.0f, s2 = 0.0f;
#pragma unroll
    for (int i = 0; i < 4; i++) {
        int c = tid + i * 256;
        float a = AF32 ? ((const float*)A)[row * EMB + c]
                       : bf2f(((const u16*)A)[row * EMB + c]);
        float t = a + bf2f(R[row * EMB + c]);
        v[i] = t;
        s += t; s2 += t * t;
    }
#pragma unroll
    for (int o = 32; o > 0; o >>= 1) {
        s  += __shfl_down(s, o);
        s2 += __shfl_down(s2, o);
    }
    if ((tid & 63) == 0) { r1[tid >> 6] = s; r2[tid >> 6] = s2; }
    __syncthreads();
    s  = r1[0] + r1[1] + r1[2] + r1[3];
    s2 = r2[0] + r2[1] + r2[2] + r2[3];

    float mu = s * (1.0f / EMB);
    float var = s2 * (1.0f / EMB) - mu * mu;
    float rs = rsqrtf(var + 1e-5f);

#pragma unroll
    for (int i = 0; i < 4; i++) {
        int c = tid + i * 256;
        float y = (v[i] - mu) * rs * w[c] + bb[c];
        if (OUTF32) ((float*)out)[row * EMB + c] = y;
        else        ((u16*)out)[row * EMB + c] = f2bf(y);
    }
}

// ---------------------------------------------------------------- launch
extern "C" void kernel_launch(void* const* d_in, const int* in_sizes, int n_in,
                              void* d_out, int out_size, void* d_ws, size_t ws_size,
                              hipStream_t stream)
{
    const float* x    = (const float*)d_in[0];
    const float* ab   = (const float*)d_in[1];
    const float* Wq   = (const float*)d_in[2];
    const float* bq   = (const float*)d_in[3];
    const float* WaK  = (const float*)d_in[4];
    const float* baK  = (const float*)d_in[5];
    const float* WbK  = (const float*)d_in[6];
    const float* bbK  = (const float*)d_in[7];
    const float* WaV  = (const float*)d_in[8];
    const float* baV  = (const float*)d_in[9];
    const float* WbV  = (const float*)d_in[10];
    const float* bbV  = (const float*)d_in[11];
    const float* Wo   = (const float*)d_in[12];
    const float* bo   = (const float*)d_in[13];
    const float* W1   = (const float*)d_in[14];
    const float* b1   = (const float*)d_in[15];
    const float* W2   = (const float*)d_in[16];
    const float* b2   = (const float*)d_in[17];
    const float* ln1w = (const float*)d_in[18];
    const float* ln1b = (const float*)d_in[19];
    const float* ln2w = (const float*)d_in[20];
    const float* ln2b = (const float*)d_in[21];

    u16* w = (u16*)d_ws;
    size_t o = 0;
    u16* WqT  = w + o; o += (size_t)EMB * EMB;
    u16* WaKT = w + o; o += (size_t)EMB * LATD;    // WaKT+WaVT contiguous = combined WT
    u16* WaVT = w + o; o += (size_t)EMB * LATD;
    u16* WbKT = w + o; o += (size_t)LATD * EMB;
    u16* WbVT = w + o; o += (size_t)LATD * EMB;
    u16* WoT  = w + o; o += (size_t)EMB * EMB;
    u16* W1T  = w + o; o += (size_t)EMB * FFND;
    u16* W2T  = w + o; o += (size_t)FFND * EMB;
    u16* Qb   = w + o; o += (size_t)TOK * EMB;
    u16* Kb   = w + o; o += (size_t)TOK * EMB;
    u16* Vb   = w + o; o += (size_t)TOK * EMB;
    u16* aOb  = w + o; o += (size_t)TOK * EMB;
    u16* projb= w + o; o += (size_t)TOK * EMB;
    u16* hb   = w + o; o += (size_t)TOK * EMB;
    u16* xb   = w + o; o += (size_t)TOK * EMB;     // bf16 x (own slot)
    float* bKV = (float*)(w + o); o += 1024;       // 512 fp32 concat bias
    // overlays (non-overlapping lifetimes):
    float* abP = (float*)projb;               // 16 MiB = projb+hb exactly; dead after fattn
    u16* KVa = aOb;                           // [TOK][512]; dead before fattn writes aOb
    u16* f1  = Qb;                            // spans Qb..aOb = TOK*FFND
    u16* f2  = projb;                         // abP/proj dead after ln1

    dim3 blk(256);

    cvt_f32_bf16_kernel<<<dim3(2048), blk, 0, stream>>>(x, xb, TOK * EMB / 8);
    concat_bias_kernel<<<dim3(2), blk, 0, stream>>>(baK, baV, bKV);
    permute_ab_kernel<<<dim3(16, 16), blk, 0, stream>>>(ab, abP);

    // merged weight transposes (tiles: 1024,256,256,256,256,1024,4096,4096 = 11264)
    TTable tt;
    tt.d[0] = {Wq,  WqT,  EMB,  EMB,  0};
    tt.d[1] = {WaK, WaKT, EMB,  LATD, 1024};
    tt.d[2] = {WaV, WaVT, EMB,  LATD, 1280};
    tt.d[3] = {WbK, WbKT, LATD, EMB,  1536};
    tt.d[4] = {WbV, WbVT, LATD, EMB,  1792};
    tt.d[5] = {Wo,  WoT,  EMB,  EMB,  2048};
    tt.d[6] = {W1,  W1T,  EMB,  FFND, 3072};
    tt.d[7] = {W2,  W2T,  FFND, EMB,  7168};
    transpose_all_kernel<<<dim3(11264), blk, 0, stream>>>(tt);

    // merged: Q = x@Wq+bq (16 n-blocks) | KVa = x@[WaK|WaV]+bKV (8 n-blocks); K=1024
    {
        GPair p;
        p.A0 = xb;  p.A1 = xb;
        p.W0 = WqT; p.W1 = WaKT;
        p.b0 = bq;  p.b1 = bKV;
        p.C0 = Qb;  p.C1 = KVa;
        p.lda0 = EMB; p.lda1 = EMB;
        p.N0 = EMB; p.N1 = 512; p.nx0 = 16;
        gemm_pair_kernel<64, 3><<<dim3(24, TOK / BM), blk, 0, stream>>>(p, EMB);
    }
    // merged: K = Ka@WbK+bbK | V = Va@WbV+bbV; K=256, both N=1024 (16+16 n-blocks)
    {
        GPair p;
        p.A0 = KVa;  p.A1 = KVa + LATD;
        p.W0 = WbKT; p.W1 = WbVT;
        p.b0 = bbK;  p.b1 = bbV;
        p.C0 = Kb;   p.C1 = Vb;
        p.lda0 = 512; p.lda1 = 512;
        p.N0 = EMB; p.N1 = EMB; p.nx0 = 16;
        gemm_pair_kernel<64, 3><<<dim3(32, TOK / BM), blk, 0, stream>>>(p, LATD);
    }

    // flash attention -> aOb                           (512 blocks)
    fattn_kernel<<<dim3(SEQ / BQ, BATCH * HEADS), blk, 0, stream>>>(Qb, Kb, Vb, abP, aOb);

    // proj = aO @ Wo + bo                              (512 blocks)
    gemm_bt_kernel<0,64,3><<<dim3(EMB / 64, TOK / BM), blk, 0, stream>>>(aOb, EMB, WoT, bo, projb, EMB, EMB);

    // h = LN(x + proj) -> bf16 hb
    ln_kernel<1,0><<<dim3(TOK), blk, 0, stream>>>(x, projb, ln1w, ln1b, hb);

    // f1 = gelu(h @ W1 + b1)                           (1024 blocks)
    gemm_bt_kernel<1,128,2><<<dim3(FFND / 128, TOK / BM), blk, 0, stream>>>(hb, EMB, W1T, b1, f1, EMB, FFND);
    // f2 = f1 @ W2 + b2                                (512 blocks)
    gemm_bt_kernel<0,64,3><<<dim3(EMB / 64, TOK / BM), blk, 0, stream>>>(f1, FFND, W2T, b2, f2, FFND, EMB);

    // out = LN(h + f2) -> fp32 d_out
    ln_kernel<0,1><<<dim3(TOK), blk, 0, stream>>>(hb, f2, ln2w, ln2b, (float*)d_out);
}